// Round 9
// baseline (852.448 us; speedup 1.0000x reference)
//
#include <hip/hip_runtime.h>
#include <hip/hip_fp16.h>
#include <math.h>

#define NN 50000
#define EE 800000

typedef _Float16 half8 __attribute__((ext_vector_type(8)));
typedef _Float16 half4t __attribute__((ext_vector_type(4)));
typedef __fp16 fp16x2 __attribute__((ext_vector_type(2)));
typedef float floatx4 __attribute__((ext_vector_type(4)));

// ---------------------------------------------------------------------------
// Fold edge-encoder into msg_w1: Wc[l][c][j], b1f[l][j].
// ---------------------------------------------------------------------------
__global__ void fold_kernel(const float* __restrict__ ew, const float* __restrict__ eb,
                            const float* __restrict__ w1, const float* __restrict__ b1,
                            float* __restrict__ Wc, float* __restrict__ b1f) {
  int l = blockIdx.y, c = blockIdx.x, j = threadIdx.x;
  __shared__ float row[128];
  const float* w1l = w1 + (size_t)l * 385 * 128;
  if (c < 32) {
    row[j] = ew[c * 128 + j];
    __syncthreads();
    float acc = 0.f;
    for (int k = 0; k < 128; k++) acc += row[k] * w1l[(256 + k) * 128 + j];
    Wc[((size_t)l * 32 + c) * 128 + j] = acc;
  } else {
    row[j] = eb[j];
    __syncthreads();
    float acc = b1[l * 128 + j];
    for (int k = 0; k < 128; k++) acc += row[k] * w1l[(256 + k) * 128 + j];
    b1f[l * 128 + j] = acc;
  }
}

// ---------------------------------------------------------------------------
// Weight packing into fp16 MFMA B-fragment order. K used as layer stride;
// grid.x = (k_range/32)*8. perm=1 bakes the GEMM2 k-permutation.
// ---------------------------------------------------------------------------
__global__ void prep_w(const float* __restrict__ src, _Float16* __restrict__ dst,
                       int K, int perm) {
  int l = blockIdx.y;
  int lane = threadIdx.x;
  int kc = blockIdx.x >> 3, nt = blockIdx.x & 7;
  int n = nt * 16 + (lane & 15);
  int k0 = kc * 32 + (lane >> 4) * 8;
  const float* s = src + (size_t)l * K * 128;
  _Float16 out[8];
  for (int j = 0; j < 8; j++) {
    int k = k0 + j;
    int ks = perm ? ((k & 7) * 16 + (k >> 3)) : k;
    out[j] = (_Float16)s[(size_t)ks * 128 + n];
  }
  _Float16* d = dst + (((size_t)l * gridDim.x + blockIdx.x) * 64 + lane) * 8;
  *(half8*)d = *(half8*)out;
}

// congestion column (mw1 row 384) -> fp16, k-perm position layout
__global__ void prep_cong(const float* __restrict__ mw1, _Float16* __restrict__ w1cp) {
  int l = blockIdx.x, p = threadIdx.x;
  int col = (p & 7) * 16 + (p >> 3);
  w1cp[l * 128 + p] = (_Float16)mw1[((size_t)l * 385 + 384) * 128 + col];
}

// ---------------------------------------------------------------------------
// CSR build: histogram, parallel 2-level scan, tiny einv scatter, then a
// fully-coalesced position-order gather pass (scatter->gather conversion).
// ---------------------------------------------------------------------------
__global__ void hist_kernel(const int* __restrict__ dstv, int* __restrict__ counts) {
  int e = blockIdx.x * 256 + threadIdx.x;
  if (e < EE) atomicAdd(&counts[dstv[e]], 1);
}

// per-block exclusive scan of 1024 counts + block totals
__global__ void scan1_kernel(const int* __restrict__ counts, int* __restrict__ offs,
                             int* __restrict__ bsum) {
  __shared__ int ws[16];
  int t = threadIdx.x, lane = t & 63, w = t >> 6;
  int i = blockIdx.x * 1024 + t;
  int v = (i < NN) ? counts[i] : 0;
  int s = v;
  for (int off = 1; off < 64; off <<= 1) {
    int u = __shfl_up(s, off);
    if (lane >= off) s += u;
  }
  if (lane == 63) ws[w] = s;
  __syncthreads();
  if (w == 0) {
    int u = (lane < 16) ? ws[lane] : 0;
    for (int off = 1; off < 16; off <<= 1) {
      int x = __shfl_up(u, off);
      if (lane >= off && lane < 16) u += x;
    }
    if (lane < 16) ws[lane] = u;
  }
  __syncthreads();
  int wbase = (w > 0) ? ws[w - 1] : 0;
  if (i < NN) offs[i] = wbase + s - v;
  if (t == 0) bsum[blockIdx.x] = ws[15];
}

// single-wave exclusive scan of the 49 block totals, in place
__global__ void scan2_kernel(int* __restrict__ bsum) {
  int t = threadIdx.x;
  int v = (t < 49) ? bsum[t] : 0;
  int s = v;
  for (int off = 1; off < 64; off <<= 1) {
    int u = __shfl_up(s, off);
    if (t >= off) s += u;
  }
  if (t < 49) bsum[t] = s - v;
}

// tiny scatter: only the inverse permutation (one random 4B store per edge)
__global__ void slot1_kernel(const int* __restrict__ dstv, const int* __restrict__ offs,
                             const int* __restrict__ bsum, int* __restrict__ cursor,
                             int* __restrict__ einv) {
  int e = blockIdx.x * 256 + threadIdx.x;
  if (e >= EE) return;
  int d = dstv[e];
  int p = offs[d] + bsum[d >> 10] + atomicAdd(&cursor[d], 1);
  einv[p] = e;
}

// position-order pass: random full-line reads (L3-assisted, no amplification),
// all writes coalesced. meta packs {src,dst}; congestion gathered later in msg.
__global__ void slot2_kernel(const int* __restrict__ einv, const int* __restrict__ srcv,
                             const int* __restrict__ dstv, const float* __restrict__ ef,
                             int2* __restrict__ meta, _Float16* __restrict__ efh) {
  int p = blockIdx.x * 256 + threadIdx.x;
  if (p >= EE) return;
  int e = einv[p];
  int2 m;
  m.x = srcv[e];
  m.y = dstv[e];
  meta[p] = m;
  const float* sp = ef + (size_t)e * 32;
  _Float16* dp = efh + (size_t)p * 32;
  for (int i = 0; i < 4; i++) {
    float4 f = *(const float4*)(sp + i * 8);
    float4 g = *(const float4*)(sp + i * 8 + 4);
    half8 v;
    v[0] = (_Float16)f.x; v[1] = (_Float16)f.y; v[2] = (_Float16)f.z; v[3] = (_Float16)f.w;
    v[4] = (_Float16)g.x; v[5] = (_Float16)g.y; v[6] = (_Float16)g.z; v[7] = (_Float16)g.w;
    *(half8*)(dp + i * 8) = v;
  }
}

// ---------------------------------------------------------------------------
// Node encoder via MFMA (writes fp16 xh) + fused SD precompute for layer 0.
// Also zeroes this block's agg slice (replaces the layer-0 memset) and
// accumulates the unrouted-mask count into red[128].
// ---------------------------------------------------------------------------
__global__ void enc_mfma(const float* __restrict__ nf, const _Float16* __restrict__ Wenc,
                         const float* __restrict__ bn, _Float16* __restrict__ xh,
                         const _Float16* __restrict__ WSa, const _Float16* __restrict__ WSb,
                         const float* __restrict__ b1f,
                         _Float16* __restrict__ Sh, _Float16* __restrict__ Dh,
                         _Float16* __restrict__ aggz,
                         const int* __restrict__ um, float* __restrict__ red) {
  __shared__ __align__(16) _Float16 hs[4][16][136];
  int t = threadIdx.x, wave = t >> 6, lane = t & 63;
  int quad = lane >> 4, l15 = lane & 15;
  long nb0 = (long)blockIdx.x * 64 + wave * 16;
  long rn = nb0 + l15;
  if (rn >= NN) rn = NN - 1;

  // zero agg slice (64 rows x 256B = 16KB; 64B/thread, coalesced)
  {
    long zn = (long)blockIdx.x * 64 + (t >> 2);
    if (zn < NN) {
      float4* p = (float4*)(aggz + (long)blockIdx.x * 64 * 128 + t * 32);
      float4 z = {};
      p[0] = z; p[1] = z; p[2] = z; p[3] = z;
    }
  }

  // umask partial count (wave 0 only; one atomic per block)
  if (t < 64) {
    long n = (long)blockIdx.x * 64 + t;
    float mv = (n < NN) ? (float)um[n] : 0.f;
    for (int off = 32; off; off >>= 1) mv += __shfl_xor(mv, off);
    if (t == 0) atomicAdd(&red[128], mv);
  }

  floatx4 acc[8] = {};
  for (int kc = 0; kc < 2; kc++) {
    const float* p = nf + rn * 64 + kc * 32 + quad * 8;
    float4 f0 = *(const float4*)p;
    float4 f1 = *(const float4*)(p + 4);
    half8 a;
    a[0] = (_Float16)f0.x; a[1] = (_Float16)f0.y;
    a[2] = (_Float16)f0.z; a[3] = (_Float16)f0.w;
    a[4] = (_Float16)f1.x; a[5] = (_Float16)f1.y;
    a[6] = (_Float16)f1.z; a[7] = (_Float16)f1.w;
    const _Float16* bp = Wenc + (size_t)(kc * 8) * 512 + lane * 8;
    for (int nt = 0; nt < 8; nt++) {
      half8 b = *(const half8*)(bp + nt * 512);
      acc[nt] = __builtin_amdgcn_mfma_f32_16x16x32_f16(a, b, acc[nt], 0, 0, 0);
    }
  }
  float bv[8];
  for (int nt = 0; nt < 8; nt++) bv[nt] = bn[nt * 16 + l15];
  for (int reg = 0; reg < 4; reg++) {
    long n = nb0 + quad * 4 + reg;
    bool ok = n < NN;
    for (int nt = 0; nt < 8; nt++) {
      _Float16 v = (_Float16)(acc[nt][reg] + bv[nt]);
      if (ok) xh[n * 128 + nt * 16 + l15] = v;
      hs[wave][quad * 4 + reg][nt * 16 + l15] = v;  // row layout for fused SD
    }
  }

  // fused SD (layer 0): per-wave private LDS slice, same-wave ds ordering
  {
    floatx4 as_[8] = {}, ad[8] = {};
#pragma unroll
    for (int kc = 0; kc < 4; kc++) {
      half8 a = *(const half8*)&hs[wave][l15][kc * 32 + quad * 8];
      const _Float16* bpa = WSa + (size_t)(kc * 8) * 512 + lane * 8;
      const _Float16* bpb = WSb + (size_t)(kc * 8) * 512 + lane * 8;
#pragma unroll
      for (int nt = 0; nt < 8; nt++) {
        half8 ba = *(const half8*)(bpa + nt * 512);
        half8 bbq = *(const half8*)(bpb + nt * 512);
        as_[nt] = __builtin_amdgcn_mfma_f32_16x16x32_f16(a, ba, as_[nt], 0, 0, 0);
        ad[nt] = __builtin_amdgcn_mfma_f32_16x16x32_f16(a, bbq, ad[nt], 0, 0, 0);
      }
    }
    float bfv[8];
    for (int nt = 0; nt < 8; nt++) bfv[nt] = b1f[nt * 16 + l15];
    for (int reg = 0; reg < 4; reg++) {
      long n = nb0 + quad * 4 + reg;
      if (n < NN) {
        half8 hsv, hdv;
        for (int nt = 0; nt < 8; nt++) {
          hsv[nt] = (_Float16)as_[nt][reg];
          hdv[nt] = (_Float16)(ad[nt][reg] + bfv[nt]);
        }
        *(half8*)(Sh + n * 128 + l15 * 8) = hsv;
        *(half8*)(Dh + n * 128 + l15 * 8) = hdv;
      }
    }
  }
}

// ---------------------------------------------------------------------------
// Message kernel v15: register-dieted 2-wave blocks at (128, 4).
// R8 showed the occupancy cap is the unified VGPR+AGPR footprint (~136 at
// budget 170 -> 3 waves/SIMD). Structural shaves to fit a 128 budget:
//   - phase E splits the 8-nt accumulation into two 4-nt passes (e[4] +
//     packed half4 results instead of e[8]: peak 24 regs vs 32);
//   - mtl1's 8 gathers issue after mtl0's first MFMA pass (not all up
//     front): loads still covered by mtl0 combine + mtl1 MFMAs.
// (128,4) then gives 8 blocks/CU (LDS 8x18.4=147KB fits) = 16 waves.
// Spill falsifier: WRITE_SIZE must stay 18.4MB.
// ---------------------------------------------------------------------------
__global__ __launch_bounds__(128, 4) void msg_kernel(
    const _Float16* __restrict__ Sh, const _Float16* __restrict__ Dh,
    const _Float16* __restrict__ efh, const int2* __restrict__ meta,
    const float* __restrict__ cong,
    const _Float16* __restrict__ Wcp, const _Float16* __restrict__ Wp2,
    const _Float16* __restrict__ w1cp, const float* __restrict__ b2,
    __half* __restrict__ agg) {
  __shared__ __align__(16) _Float16 As[64][136];  // h-tile then m-tile
  __shared__ int s_src[64], s_dst[64];
  __shared__ float s_cg[64];
  int t = threadIdx.x, wave = t >> 6, lane = t & 63;
  int quad = lane >> 4, l15 = lane & 15;
  long eb0 = (long)blockIdx.x * 64;
  int web = wave * 32;

  if (t < 64) {
    int2 m = meta[eb0 + t];
    s_src[t] = m.x;
    s_dst[t] = m.y;
    s_cg[t] = cong[m.x];  // 200KB array: L2-resident gather
  }
  // streaming loads independent of meta: issue before the barrier
  half8 wcl = *(const half8*)(w1cp + l15 * 8);
  half8 av0 = *(const half8*)(efh + (size_t)(eb0 + web + l15) * 32 + quad * 8);
  half8 av1 = *(const half8*)(efh + (size_t)(eb0 + web + 16 + l15) * 32 + quad * 8);
  __syncthreads();

  // mtl0 gathers (mtl1's issue later, inside mtl0's phase E)
  half8 sv0[4], dv0[4];
#pragma unroll
  for (int reg = 0; reg < 4; reg++) {
    int r = web + quad * 4 + reg;
    sv0[reg] = *(const half8*)(Sh + (size_t)s_src[r] * 128 + l15 * 8);
    dv0[reg] = *(const half8*)(Dh + (size_t)s_dst[r] * 128 + l15 * 8);
  }

  // ---- phase E, mtl0: pass A (nt 0..3) ----
  floatx4 e[4] = {};
#pragma unroll
  for (int nt = 0; nt < 4; nt++) {
    half8 b = *(const half8*)(Wcp + (size_t)nt * 512 + lane * 8);
    e[nt] = __builtin_amdgcn_mfma_f32_16x16x32_f16(av0, b, e[nt], 0, 0, 0);
  }
  // issue mtl1 gathers now: in flight across mtl0 combine + mtl1 MFMAs
  half8 sv1[4], dv1[4];
#pragma unroll
  for (int reg = 0; reg < 4; reg++) {
    int r = web + 16 + quad * 4 + reg;
    sv1[reg] = *(const half8*)(Sh + (size_t)s_src[r] * 128 + l15 * 8);
    dv1[reg] = *(const half8*)(Dh + (size_t)s_dst[r] * 128 + l15 * 8);
  }
  half4t pkl[4], pkh[4];
#pragma unroll
  for (int reg = 0; reg < 4; reg++)
#pragma unroll
    for (int i = 0; i < 2; i++) {
      fp16x2 p = __builtin_amdgcn_cvt_pkrtz(e[2 * i][reg], e[2 * i + 1][reg]);
      pkl[reg][2 * i] = (_Float16)p[0];
      pkl[reg][2 * i + 1] = (_Float16)p[1];
    }
  // ---- phase E, mtl0: pass B (nt 4..7) ----
#pragma unroll
  for (int nt = 0; nt < 4; nt++) {
    half8 b = *(const half8*)(Wcp + (size_t)(nt + 4) * 512 + lane * 8);
    e[nt] = {};
    e[nt] = __builtin_amdgcn_mfma_f32_16x16x32_f16(av0, b, e[nt], 0, 0, 0);
  }
#pragma unroll
  for (int reg = 0; reg < 4; reg++)
#pragma unroll
    for (int i = 0; i < 2; i++) {
      fp16x2 p = __builtin_amdgcn_cvt_pkrtz(e[2 * i][reg], e[2 * i + 1][reg]);
      pkh[reg][2 * i] = (_Float16)p[0];
      pkh[reg][2 * i + 1] = (_Float16)p[1];
    }
  // ---- mtl0 combine + store ----
#pragma unroll
  for (int reg = 0; reg < 4; reg++) {
    int r = web + quad * 4 + reg;
    _Float16 cgh = (_Float16)s_cg[r];
    half8 v = sv0[reg] + dv0[reg];
    half8 e8;
#pragma unroll
    for (int i = 0; i < 4; i++) { e8[i] = pkl[reg][i]; e8[4 + i] = pkh[reg][i]; }
    v += e8;
    v += wcl * cgh;
#pragma unroll
    for (int i = 0; i < 8; i++) v[i] = v[i] > (_Float16)0 ? v[i] : (_Float16)0;
    *(half8*)&As[r][l15 * 8] = v;
  }

  // ---- phase E, mtl1: pass A ----
#pragma unroll
  for (int nt = 0; nt < 4; nt++) {
    half8 b = *(const half8*)(Wcp + (size_t)nt * 512 + lane * 8);
    e[nt] = {};
    e[nt] = __builtin_amdgcn_mfma_f32_16x16x32_f16(av1, b, e[nt], 0, 0, 0);
  }
#pragma unroll
  for (int reg = 0; reg < 4; reg++)
#pragma unroll
    for (int i = 0; i < 2; i++) {
      fp16x2 p = __builtin_amdgcn_cvt_pkrtz(e[2 * i][reg], e[2 * i + 1][reg]);
      pkl[reg][2 * i] = (_Float16)p[0];
      pkl[reg][2 * i + 1] = (_Float16)p[1];
    }
  // ---- phase E, mtl1: pass B ----
#pragma unroll
  for (int nt = 0; nt < 4; nt++) {
    half8 b = *(const half8*)(Wcp + (size_t)(nt + 4) * 512 + lane * 8);
    e[nt] = {};
    e[nt] = __builtin_amdgcn_mfma_f32_16x16x32_f16(av1, b, e[nt], 0, 0, 0);
  }
#pragma unroll
  for (int reg = 0; reg < 4; reg++)
#pragma unroll
    for (int i = 0; i < 2; i++) {
      fp16x2 p = __builtin_amdgcn_cvt_pkrtz(e[2 * i][reg], e[2 * i + 1][reg]);
      pkh[reg][2 * i] = (_Float16)p[0];
      pkh[reg][2 * i + 1] = (_Float16)p[1];
    }
  // ---- mtl1 combine + store ----
#pragma unroll
  for (int reg = 0; reg < 4; reg++) {
    int r = web + 16 + quad * 4 + reg;
    _Float16 cgh = (_Float16)s_cg[r];
    half8 v = sv1[reg] + dv1[reg];
    half8 e8;
#pragma unroll
    for (int i = 0; i < 4; i++) { e8[i] = pkl[reg][i]; e8[4 + i] = pkh[reg][i]; }
    v += e8;
    v += wcl * cgh;
#pragma unroll
    for (int i = 0; i < 8; i++) v[i] = v[i] > (_Float16)0 ? v[i] : (_Float16)0;
    *(half8*)&As[r][l15 * 8] = v;
  }
  __syncthreads();

  // GEMM2 (N-split): wave owns N-tiles nb..nb+3
  int nb = wave * 4;
  floatx4 acc2[4][4] = {};  // [mt][ntp]
  __builtin_amdgcn_s_setprio(1);
#pragma unroll
  for (int kc = 0; kc < 4; kc++) {
    const _Float16* bp = Wp2 + ((size_t)(kc * 8 + nb)) * 512 + lane * 8;
    half8 b0 = *(const half8*)bp;
    half8 b1v = *(const half8*)(bp + 512);
    half8 b2v = *(const half8*)(bp + 1024);
    half8 b3v = *(const half8*)(bp + 1536);
#pragma unroll
    for (int mt = 0; mt < 4; mt++) {
      half8 a = *(const half8*)&As[mt * 16 + l15][kc * 32 + quad * 8];
      acc2[mt][0] = __builtin_amdgcn_mfma_f32_16x16x32_f16(a, b0, acc2[mt][0], 0, 0, 0);
      acc2[mt][1] = __builtin_amdgcn_mfma_f32_16x16x32_f16(a, b1v, acc2[mt][1], 0, 0, 0);
      acc2[mt][2] = __builtin_amdgcn_mfma_f32_16x16x32_f16(a, b2v, acc2[mt][2], 0, 0, 0);
      acc2[mt][3] = __builtin_amdgcn_mfma_f32_16x16x32_f16(a, b3v, acc2[mt][3], 0, 0, 0);
    }
  }
  __builtin_amdgcn_s_setprio(0);
  __syncthreads();

  // epilogue: bias + direct per-lane b16 stores (all 64 lanes active, no shfl)
  {
    float c[4];
#pragma unroll
    for (int ntp = 0; ntp < 4; ntp++) c[ntp] = b2[(nb + ntp) * 16 + l15];
#pragma unroll
    for (int mt = 0; mt < 4; mt++)
#pragma unroll
      for (int reg = 0; reg < 4; reg++) {
        int row = mt * 16 + quad * 4 + reg;
#pragma unroll
        for (int ntp = 0; ntp < 4; ntp++)
          As[row][(nb + ntp) * 16 + l15] = (_Float16)(acc2[mt][ntp][reg] + c[ntp]);
      }
  }
  __syncthreads();

  // segmented reduction over sorted dst runs (fp16x2 accumulate; agg is fp16
  // RMW-atomic anyway so accumulation precision class is unchanged)
  {
    int cp = lane;
    int r0 = wave * 32;
    __half2 vals[32];
#pragma unroll
    for (int i = 0; i < 32; i++) vals[i] = *(__half2*)&As[r0 + i][cp * 2];
    int cur = s_dst[r0];
    __half2 acc = __float2half2_rn(0.f);
    for (int i = 0; i < 32; i++) {
      int d = s_dst[r0 + i];
      if (d != cur) {
        unsafeAtomicAdd((__half2*)(agg + (long)cur * 128 + cp * 2), acc);
        acc = __float2half2_rn(0.f);
        cur = d;
      }
      acc = __hadd2(acc, vals[i]);
    }
    unsafeAtomicAdd((__half2*)(agg + (long)cur * 128 + cp * 2), acc);
  }
}

// ---------------------------------------------------------------------------
// Update + residual + layernorm (MFMA), with fused SD precompute for the NEXT
// layer (+ agg-slice zeroing). DO_RED is compile-time so layers 0..2 pay no
// register cost for the fused channel-sum.
// ---------------------------------------------------------------------------
template <bool DO_RED>
__global__ __launch_bounds__(256, 3) void upd_kernel(
    _Float16* __restrict__ xh, _Float16* __restrict__ agg,
    const _Float16* __restrict__ Wp1, const _Float16* __restrict__ Wp2,
    const float* __restrict__ b1, const float* __restrict__ b2,
    const float* __restrict__ g, const float* __restrict__ bb,
    const _Float16* __restrict__ WSa, const _Float16* __restrict__ WSb,
    const float* __restrict__ b1f,
    _Float16* __restrict__ Sh, _Float16* __restrict__ Dh,
    float* __restrict__ red) {
  __shared__ __align__(16) _Float16 hs[4][16][136];
  int t = threadIdx.x, wave = t >> 6, lane = t & 63;
  int quad = lane >> 4, l15 = lane & 15;
  long nb0 = (long)blockIdx.x * 64 + wave * 16;

  floatx4 acc[8] = {};
  {
    long n = nb0 + l15;
    long rn = n < NN ? n : NN - 1;
    for (int kc = 0; kc < 8; kc++) {
      half8 a;
      if (kc < 4) {
        a = *(const half8*)(xh + rn * 128 + kc * 32 + quad * 8);
      } else {
        a = *(const half8*)(agg + rn * 128 + (kc - 4) * 32 + quad * 8);
      }
      const _Float16* bp = Wp1 + (size_t)(kc * 8) * 512 + lane * 8;
      for (int nt = 0; nt < 8; nt++) {
        half8 b = *(const half8*)(bp + nt * 512);
        acc[nt] = __builtin_amdgcn_mfma_f32_16x16x32_f16(a, b, acc[nt], 0, 0, 0);
      }
    }
  }

  float bbv[8];
  for (int nt = 0; nt < 8; nt++) bbv[nt] = b1[nt * 16 + l15];
  for (int reg = 0; reg < 4; reg++) {
    half8 hv;
    for (int nt = 0; nt < 8; nt++)
      hv[nt] = (_Float16)fmaxf(acc[nt][reg] + bbv[nt], 0.f);
    *(half8*)&hs[wave][quad * 4 + reg][l15 * 8] = hv;
  }
  __syncthreads();

  floatx4 acc2[8] = {};
  for (int kc = 0; kc < 4; kc++) {
    half8 a = *(const half8*)&hs[wave][l15][kc * 32 + quad * 8];
    const _Float16* bp = Wp2 + (size_t)(kc * 8) * 512 + lane * 8;
    for (int nt = 0; nt < 8; nt++) {
      half8 b = *(const half8*)(bp + nt * 512);
      acc2[nt] = __builtin_amdgcn_mfma_f32_16x16x32_f16(a, b, acc2[nt], 0, 0, 0);
    }
  }

  float b2v[8], gv[8], bv[8];
  for (int nt = 0; nt < 8; nt++) {
    int col = nt * 16 + l15;
    b2v[nt] = b2[col]; gv[nt] = g[col]; bv[nt] = bb[col];
  }
  bool fuse = (WSa != nullptr);
  float cs[DO_RED ? 8 : 1];
  if (DO_RED)
    for (int nt = 0; nt < (DO_RED ? 8 : 1); nt++) cs[nt] = 0.f;
  for (int reg = 0; reg < 4; reg++) {
    long n = nb0 + quad * 4 + reg;
    bool ok = n < NN;
    long rn = ok ? n : NN - 1;
    float y[8];
    float s = 0.f;
    for (int nt = 0; nt < 8; nt++) {
      y[nt] = (float)xh[rn * 128 + nt * 16 + l15] + acc2[nt][reg] + b2v[nt];
      s += y[nt];
    }
    s += __shfl_xor(s, 1); s += __shfl_xor(s, 2);
    s += __shfl_xor(s, 4); s += __shfl_xor(s, 8);
    float mu = s * (1.f / 128.f);
    float q = 0.f;
    for (int nt = 0; nt < 8; nt++) {
      y[nt] -= mu;
      q += y[nt] * y[nt];
    }
    q += __shfl_xor(q, 1); q += __shfl_xor(q, 2);
    q += __shfl_xor(q, 4); q += __shfl_xor(q, 8);
    float rstd = rsqrtf(q * (1.f / 128.f) + 1e-5f);
    for (int nt = 0; nt < 8; nt++) {
      _Float16 o = (_Float16)(y[nt] * rstd * gv[nt] + bv[nt]);
      if (ok) xh[n * 128 + nt * 16 + l15] = o;
      if (fuse) hs[wave][quad * 4 + reg][nt * 16 + l15] = o;  // row layout
      if (DO_RED) cs[nt] += ok ? (float)o : 0.f;
    }
  }

  // fused SD for the next layer (per-wave private LDS slice; same-wave
  // ds_write->ds_read ordering handled by compiler-inserted lgkmcnt)
  if (fuse) {
    floatx4 as_[8] = {}, ad[8] = {};
#pragma unroll
    for (int kc = 0; kc < 4; kc++) {
      half8 a = *(const half8*)&hs[wave][l15][kc * 32 + quad * 8];
      const _Float16* bpa = WSa + (size_t)(kc * 8) * 512 + lane * 8;
      const _Float16* bpb = WSb + (size_t)(kc * 8) * 512 + lane * 8;
#pragma unroll
      for (int nt = 0; nt < 8; nt++) {
        half8 ba = *(const half8*)(bpa + nt * 512);
        half8 bbq = *(const half8*)(bpb + nt * 512);
        as_[nt] = __builtin_amdgcn_mfma_f32_16x16x32_f16(a, ba, as_[nt], 0, 0, 0);
        ad[nt] = __builtin_amdgcn_mfma_f32_16x16x32_f16(a, bbq, ad[nt], 0, 0, 0);
      }
    }
    float bfv[8];
    for (int nt = 0; nt < 8; nt++) bfv[nt] = b1f[nt * 16 + l15];
    for (int reg = 0; reg < 4; reg++) {
      long n = nb0 + quad * 4 + reg;
      if (n < NN) {
        half8 hsv, hdv;
        for (int nt = 0; nt < 8; nt++) {
          hsv[nt] = (_Float16)as_[nt][reg];
          hdv[nt] = (_Float16)(ad[nt][reg] + bfv[nt]);
        }
        *(half8*)(Sh + n * 128 + l15 * 8) = hsv;
        *(half8*)(Dh + n * 128 + l15 * 8) = hdv;
      }
    }

    // zero agg slice for the next msg pass (all reads of agg done above;
    // only this block's lanes ever touch these rows -> race-free)
    long zn = (long)blockIdx.x * 64 + (t >> 2);
    if (zn < NN) {
      float4* p = (float4*)(agg + (long)blockIdx.x * 64 * 128 + t * 32);
      float4 z = {};
      p[0] = z; p[1] = z; p[2] = z; p[3] = z;
    }
  }

  // fused channel-sum on the last layer: block-reduce via hs, 128 atomics
  if (DO_RED) {
    for (int nt = 0; nt < 8; nt++) {
      cs[nt] += __shfl_xor(cs[nt], 16);
      cs[nt] += __shfl_xor(cs[nt], 32);
    }
    __syncthreads();  // all hs reads done (fuse==false on last layer)
    float* hsF = (float*)hs;
    if (quad == 0)
      for (int nt = 0; nt < 8; nt++) hsF[wave * 128 + nt * 16 + l15] = cs[nt];
    __syncthreads();
    if (t < 128)
      atomicAdd(&red[t], hsF[t] + hsF[128 + t] + hsF[256 + t] + hsF[384 + t]);
  }
}

// ---------------------------------------------------------------------------
// Readout head.
// ---------------------------------------------------------------------------
__global__ void readout_kernel(const float* __restrict__ red,
                               const float* __restrict__ xw1, const float* __restrict__ xb1,
                               const float* __restrict__ xw2, const float* __restrict__ xb2,
                               const float* __restrict__ rw1, const float* __restrict__ rb1,
                               const float* __restrict__ rw2, const float* __restrict__ rb2,
                               const float* __restrict__ rw3, const float* __restrict__ rb3,
                               float* __restrict__ out) {
  __shared__ float sa[128], sb[128], sc[128];
  int j = threadIdx.x;
  const float inv = 1.f / (float)NN;
  float ge = red[j] * inv;
  float uf = red[128] * inv;
  float u1 = fmaxf(uf * xw1[j] + xb1[j], 0.f);
  sa[j] = u1;
  sb[j] = ge;
  __syncthreads();
  float u2 = xb2[j];
  for (int k = 0; k < 128; k++) u2 += sa[k] * xw2[k * 128 + j];
  sc[j] = u2;
  __syncthreads();
  float h1 = rb1[j];
  for (int k = 0; k < 128; k++) h1 += sb[k] * rw1[k * 128 + j];
  for (int k = 0; k < 128; k++) h1 += sc[k] * rw1[(128 + k) * 128 + j];
  h1 = fmaxf(h1, 0.f);
  __syncthreads();
  sa[j] = h1;
  __syncthreads();
  float h2 = 0.f;
  if (j < 64) {
    h2 = rb2[j];
    for (int k = 0; k < 128; k++) h2 += sa[k] * rw2[k * 64 + j];
    h2 = fmaxf(h2, 0.f);
  }
  __syncthreads();
  if (j < 64) sb[j] = h2;
  __syncthreads();
  if (j == 0) {
    float a = rb3[0];
    for (int k = 0; k < 64; k++) a += sb[k] * rw3[k];
    out[0] = 1.f / (1.f + expf(-a));
  }
}

// ---------------------------------------------------------------------------
extern "C" void kernel_launch(void* const* d_in, const int* in_sizes, int n_in,
                              void* d_out, int out_size, void* d_ws, size_t ws_size,
                              hipStream_t stream) {
  const float* nf   = (const float*)d_in[0];
  const float* ef   = (const float*)d_in[1];
  const float* cong = (const float*)d_in[2];
  const int*   eidx = (const int*)d_in[3];
  const int*   um   = (const int*)d_in[4];
  const float* enw  = (const float*)d_in[5];
  const float* enb  = (const float*)d_in[6];
  const float* eew  = (const float*)d_in[7];
  const float* eeb  = (const float*)d_in[8];
  const float* mw1  = (const float*)d_in[9];
  const float* mb1  = (const float*)d_in[10];
  const float* mw2  = (const float*)d_in[11];
  const float* mb2  = (const float*)d_in[12];
  const float* uw1  = (const float*)d_in[13];
  const float* ub1  = (const float*)d_in[14];
  const float* uw2  = (const float*)d_in[15];
  const float* ub2  = (const float*)d_in[16];
  const float* lnw  = (const float*)d_in[17];
  const float* lnb  = (const float*)d_in[18];
  const float* xw1  = (const float*)d_in[19];
  const float* xb1  = (const float*)d_in[20];
  const float* xw2  = (const float*)d_in[21];
  const float* xb2  = (const float*)d_in[22];
  const float* rw1  = (const float*)d_in[23];
  const float* rb1  = (const float*)d_in[24];
  const float* rw2  = (const float*)d_in[25];
  const float* rb2  = (const float*)d_in[26];
  const float* rw3  = (const float*)d_in[27];
  const float* rb3  = (const float*)d_in[28];
  float* out = (float*)d_out;

  char* W = (char*)d_ws;
  _Float16* xh    = (_Float16*)(W + 0);          // 12,800,000
  __half*   agg   = (__half*)(W + 12800000);     // 12,800,000
  _Float16* efh   = (_Float16*)(W + 25600000);   // 51,200,000
  _Float16* Sh    = (_Float16*)(W + 76800000);   // 12,800,000
  _Float16* Dh    = (_Float16*)(W + 89600000);   // 12,800,000
  int2*     meta  = (int2*)(W + 102400000);      // 6,400,000
  int*      einv  = (int*)(W + 108800000);       // 3,200,000
  int*      counts= (int*)(W + 112000000);       // 200,000
  int*      cursor= (int*)(W + 112200000);       // 200,000
  int*      offs  = (int*)(W + 112400000);       // 200,000
  _Float16* WSa   = (_Float16*)(W + 112600000);  // 131,072
  _Float16* WSb   = (_Float16*)(W + 112731072);  // 131,072
  _Float16* Wcp   = (_Float16*)(W + 112862144);  // 32,768
  _Float16* Wm2   = (_Float16*)(W + 112894912);  // 131,072
  _Float16* Wu1   = (_Float16*)(W + 113025984);  // 262,144
  _Float16* Wu2   = (_Float16*)(W + 113288128);  // 131,072
  _Float16* Wen   = (_Float16*)(W + 113419200);  // 16,384
  float*    Wc    = (float*)(W + 113435584);     // 65,536
  float*    b1f   = (float*)(W + 113501120);     // 2,048
  _Float16* w1cp  = (_Float16*)(W + 113503168);  // 1,024
  float*    red   = (float*)(W + 113504192);     // 516
  // bsum (49 ints = 196B) aliases red: bsum lives during CSR build (start of
  // launch; slot1 is its last reader); red is memset just before enc and used
  // from enc onward. Lifetimes disjoint, stream-ordered.
  int*      bsum  = (int*)red;

  const int* srcv = eidx;
  const int* dstv = eidx + EE;

  // CSR build: hist -> 2-level parallel scan -> einv scatter -> coalesced gather
  (void)hipMemsetAsync(counts, 0, 400000, stream);  // counts + cursor
  hist_kernel<<<3125, 256, 0, stream>>>(dstv, counts);
  scan1_kernel<<<49, 1024, 0, stream>>>(counts, offs, bsum);
  scan2_kernel<<<1, 64, 0, stream>>>(bsum);
  slot1_kernel<<<3125, 256, 0, stream>>>(dstv, offs, bsum, cursor, einv);
  slot2_kernel<<<3125, 256, 0, stream>>>(einv, srcv, dstv, ef, meta, efh);

  // weight prep + encoder (enc fuses SD for layer 0 + agg zero + umask count)
  fold_kernel<<<dim3(33, 4), 128, 0, stream>>>(eew, eeb, mw1, mb1, Wc, b1f);
  prep_w<<<dim3(8, 4), 64, 0, stream>>>(Wc, Wcp, 32, 0);
  prep_w<<<dim3(32, 4), 64, 0, stream>>>(mw1, WSa, 385, 0);
  prep_w<<<dim3(32, 4), 64, 0, stream>>>(mw1 + 128 * 128, WSb, 385, 0);
  prep_w<<<dim3(32, 4), 64, 0, stream>>>(mw2, Wm2, 128, 1);
  prep_w<<<dim3(64, 4), 64, 0, stream>>>(uw1, Wu1, 256, 0);
  prep_w<<<dim3(32, 4), 64, 0, stream>>>(uw2, Wu2, 128, 1);
  prep_w<<<dim3(16, 1), 64, 0, stream>>>(enw, Wen, 64, 0);
  prep_cong<<<4, 128, 0, stream>>>(mw1, w1cp);
  // red memset AFTER slot1 (bsum alias) and BEFORE enc (umask accumulation)
  (void)hipMemsetAsync(red, 0, 129 * sizeof(float), stream);
  enc_mfma<<<782, 256, 0, stream>>>(nf, Wen, enb, xh, WSa, WSb, b1f, Sh, Dh,
                                    (_Float16*)agg, um, red);

  for (int l = 0; l < 4; l++) {
    msg_kernel<<<12500, 128, 0, stream>>>(
        Sh, Dh, efh, meta, cong,
        Wcp + (size_t)l * 8 * 512, Wm2 + (size_t)l * 32 * 512,
        w1cp + l * 128, mb2 + l * 128, agg);
    if (l < 3) {
      upd_kernel<false><<<782, 256, 0, stream>>>(
          xh, (_Float16*)agg,
          Wu1 + (size_t)l * 64 * 512, Wu2 + (size_t)l * 32 * 512,
          ub1 + l * 128, ub2 + l * 128, lnw + l * 128, lnb + l * 128,
          WSa + (size_t)(l + 1) * 32 * 512, WSb + (size_t)(l + 1) * 32 * 512,
          b1f + (l + 1) * 128, Sh, Dh, red);
    } else {
      upd_kernel<true><<<782, 256, 0, stream>>>(
          xh, (_Float16*)agg,
          Wu1 + (size_t)l * 64 * 512, Wu2 + (size_t)l * 32 * 512,
          ub1 + l * 128, ub2 + l * 128, lnw + l * 128, lnb + l * 128,
          (const _Float16*)nullptr, (const _Float16*)nullptr,
          (const float*)nullptr, Sh, Dh, red);
    }
  }

  readout_kernel<<<1, 128, 0, stream>>>(red, xw1, xb1, xw2, xb2,
                                        rw1, rb1, rw2, rb2, rw3, rb3, out);
}

// Round 11
// 803.548 us; speedup vs baseline: 1.0609x; 1.0609x over previous
//
#include <hip/hip_runtime.h>
#include <hip/hip_fp16.h>
#include <math.h>

#define NN 50000
#define EE 800000

typedef _Float16 half8 __attribute__((ext_vector_type(8)));
typedef __fp16 fp16x2 __attribute__((ext_vector_type(2)));
typedef float floatx4 __attribute__((ext_vector_type(4)));

// ---------------------------------------------------------------------------
// Fold edge-encoder into msg_w1: Wc[l][c][j], b1f[l][j].
// ---------------------------------------------------------------------------
__global__ void fold_kernel(const float* __restrict__ ew, const float* __restrict__ eb,
                            const float* __restrict__ w1, const float* __restrict__ b1,
                            float* __restrict__ Wc, float* __restrict__ b1f) {
  int l = blockIdx.y, c = blockIdx.x, j = threadIdx.x;
  __shared__ float row[128];
  const float* w1l = w1 + (size_t)l * 385 * 128;
  if (c < 32) {
    row[j] = ew[c * 128 + j];
    __syncthreads();
    float acc = 0.f;
    for (int k = 0; k < 128; k++) acc += row[k] * w1l[(256 + k) * 128 + j];
    Wc[((size_t)l * 32 + c) * 128 + j] = acc;
  } else {
    row[j] = eb[j];
    __syncthreads();
    float acc = b1[l * 128 + j];
    for (int k = 0; k < 128; k++) acc += row[k] * w1l[(256 + k) * 128 + j];
    b1f[l * 128 + j] = acc;
  }
}

// ---------------------------------------------------------------------------
// Weight packing into fp16 MFMA B-fragment order. K used as layer stride;
// grid.x = (k_range/32)*8. perm=1 bakes the GEMM2 k-permutation.
// ---------------------------------------------------------------------------
__global__ void prep_w(const float* __restrict__ src, _Float16* __restrict__ dst,
                       int K, int perm) {
  int l = blockIdx.y;
  int lane = threadIdx.x;
  int kc = blockIdx.x >> 3, nt = blockIdx.x & 7;
  int n = nt * 16 + (lane & 15);
  int k0 = kc * 32 + (lane >> 4) * 8;
  const float* s = src + (size_t)l * K * 128;
  _Float16 out[8];
  for (int j = 0; j < 8; j++) {
    int k = k0 + j;
    int ks = perm ? ((k & 7) * 16 + (k >> 3)) : k;
    out[j] = (_Float16)s[(size_t)ks * 128 + n];
  }
  _Float16* d = dst + (((size_t)l * gridDim.x + blockIdx.x) * 64 + lane) * 8;
  *(half8*)d = *(half8*)out;
}

// congestion column (mw1 row 384) -> fp16, k-perm position layout
__global__ void prep_cong(const float* __restrict__ mw1, _Float16* __restrict__ w1cp) {
  int l = blockIdx.x, p = threadIdx.x;
  int col = (p & 7) * 16 + (p >> 3);
  w1cp[l * 128 + p] = (_Float16)mw1[((size_t)l * 385 + 384) * 128 + col];
}

// ---------------------------------------------------------------------------
// CSR build: histogram (storing each edge's intra-bucket rank from the
// returned atomic counter), parallel 2-level scan, ATOMIC-FREE einv scatter,
// then the coalesced position-order gather pass.
// ---------------------------------------------------------------------------
__global__ void hist_kernel(const int* __restrict__ dstv, int* __restrict__ counts,
                            int* __restrict__ rank) {
  int e = blockIdx.x * 256 + threadIdx.x;
  if (e < EE) rank[e] = atomicAdd(&counts[dstv[e]], 1);
}

// per-block exclusive scan of 1024 counts + block totals
__global__ void scan1_kernel(const int* __restrict__ counts, int* __restrict__ offs,
                             int* __restrict__ bsum) {
  __shared__ int ws[16];
  int t = threadIdx.x, lane = t & 63, w = t >> 6;
  int i = blockIdx.x * 1024 + t;
  int v = (i < NN) ? counts[i] : 0;
  int s = v;
  for (int off = 1; off < 64; off <<= 1) {
    int u = __shfl_up(s, off);
    if (lane >= off) s += u;
  }
  if (lane == 63) ws[w] = s;
  __syncthreads();
  if (w == 0) {
    int u = (lane < 16) ? ws[lane] : 0;
    for (int off = 1; off < 16; off <<= 1) {
      int x = __shfl_up(u, off);
      if (lane >= off && lane < 16) u += x;
    }
    if (lane < 16) ws[lane] = u;
  }
  __syncthreads();
  int wbase = (w > 0) ? ws[w - 1] : 0;
  if (i < NN) offs[i] = wbase + s - v;
  if (t == 0) bsum[blockIdx.x] = ws[15];
}

// single-wave exclusive scan of the 49 block totals, in place
__global__ void scan2_kernel(int* __restrict__ bsum) {
  int t = threadIdx.x;
  int v = (t < 49) ? bsum[t] : 0;
  int s = v;
  for (int off = 1; off < 64; off <<= 1) {
    int u = __shfl_up(s, off);
    if (t >= off) s += u;
  }
  if (t < 49) bsum[t] = s - v;
}

// atomic-free inverse permutation: p = offs[d] + bsum-chunk + rank[e]
__global__ void slot1_kernel(const int* __restrict__ dstv, const int* __restrict__ offs,
                             const int* __restrict__ bsum, const int* __restrict__ rank,
                             int* __restrict__ einv) {
  int e = blockIdx.x * 256 + threadIdx.x;
  if (e >= EE) return;
  int d = dstv[e];
  int p = offs[d] + bsum[d >> 10] + rank[e];
  einv[p] = e;
}

// position-order pass: random full-line reads (L3-assisted, no amplification),
// all writes coalesced. meta packs {src,dst}; congestion gathered later in msg.
__global__ void slot2_kernel(const int* __restrict__ einv, const int* __restrict__ srcv,
                             const int* __restrict__ dstv, const float* __restrict__ ef,
                             int2* __restrict__ meta, _Float16* __restrict__ efh) {
  int p = blockIdx.x * 256 + threadIdx.x;
  if (p >= EE) return;
  int e = einv[p];
  int2 m;
  m.x = srcv[e];
  m.y = dstv[e];
  meta[p] = m;
  const float* sp = ef + (size_t)e * 32;
  _Float16* dp = efh + (size_t)p * 32;
  for (int i = 0; i < 4; i++) {
    float4 f = *(const float4*)(sp + i * 8);
    float4 g = *(const float4*)(sp + i * 8 + 4);
    half8 v;
    v[0] = (_Float16)f.x; v[1] = (_Float16)f.y; v[2] = (_Float16)f.z; v[3] = (_Float16)f.w;
    v[4] = (_Float16)g.x; v[5] = (_Float16)g.y; v[6] = (_Float16)g.z; v[7] = (_Float16)g.w;
    *(half8*)(dp + i * 8) = v;
  }
}

// ---------------------------------------------------------------------------
// Node encoder via MFMA (writes fp16 xh) + fused SD precompute for layer 0.
// Also zeroes this block's agg slice (replaces the layer-0 memset) and
// accumulates the unrouted-mask count into red[128].
// ---------------------------------------------------------------------------
__global__ void enc_mfma(const float* __restrict__ nf, const _Float16* __restrict__ Wenc,
                         const float* __restrict__ bn, _Float16* __restrict__ xh,
                         const _Float16* __restrict__ WSa, const _Float16* __restrict__ WSb,
                         const float* __restrict__ b1f,
                         _Float16* __restrict__ Sh, _Float16* __restrict__ Dh,
                         _Float16* __restrict__ aggz,
                         const int* __restrict__ um, float* __restrict__ red) {
  __shared__ __align__(16) _Float16 hs[4][16][136];
  int t = threadIdx.x, wave = t >> 6, lane = t & 63;
  int quad = lane >> 4, l15 = lane & 15;
  long nb0 = (long)blockIdx.x * 64 + wave * 16;
  long rn = nb0 + l15;
  if (rn >= NN) rn = NN - 1;

  // zero agg slice (64 rows x 256B = 16KB; 64B/thread, coalesced)
  {
    long zn = (long)blockIdx.x * 64 + (t >> 2);
    if (zn < NN) {
      float4* p = (float4*)(aggz + (long)blockIdx.x * 64 * 128 + t * 32);
      float4 z = {};
      p[0] = z; p[1] = z; p[2] = z; p[3] = z;
    }
  }

  // umask partial count (wave 0 only; one atomic per block)
  if (t < 64) {
    long n = (long)blockIdx.x * 64 + t;
    float mv = (n < NN) ? (float)um[n] : 0.f;
    for (int off = 32; off; off >>= 1) mv += __shfl_xor(mv, off);
    if (t == 0) atomicAdd(&red[128], mv);
  }

  floatx4 acc[8] = {};
  for (int kc = 0; kc < 2; kc++) {
    const float* p = nf + rn * 64 + kc * 32 + quad * 8;
    float4 f0 = *(const float4*)p;
    float4 f1 = *(const float4*)(p + 4);
    half8 a;
    a[0] = (_Float16)f0.x; a[1] = (_Float16)f0.y;
    a[2] = (_Float16)f0.z; a[3] = (_Float16)f0.w;
    a[4] = (_Float16)f1.x; a[5] = (_Float16)f1.y;
    a[6] = (_Float16)f1.z; a[7] = (_Float16)f1.w;
    const _Float16* bp = Wenc + (size_t)(kc * 8) * 512 + lane * 8;
    for (int nt = 0; nt < 8; nt++) {
      half8 b = *(const half8*)(bp + nt * 512);
      acc[nt] = __builtin_amdgcn_mfma_f32_16x16x32_f16(a, b, acc[nt], 0, 0, 0);
    }
  }
  float bv[8];
  for (int nt = 0; nt < 8; nt++) bv[nt] = bn[nt * 16 + l15];
  for (int reg = 0; reg < 4; reg++) {
    long n = nb0 + quad * 4 + reg;
    bool ok = n < NN;
    for (int nt = 0; nt < 8; nt++) {
      _Float16 v = (_Float16)(acc[nt][reg] + bv[nt]);
      if (ok) xh[n * 128 + nt * 16 + l15] = v;
      hs[wave][quad * 4 + reg][nt * 16 + l15] = v;  // row layout for fused SD
    }
  }

  // fused SD (layer 0): per-wave private LDS slice, same-wave ds ordering
  {
    floatx4 as_[8] = {}, ad[8] = {};
#pragma unroll
    for (int kc = 0; kc < 4; kc++) {
      half8 a = *(const half8*)&hs[wave][l15][kc * 32 + quad * 8];
      const _Float16* bpa = WSa + (size_t)(kc * 8) * 512 + lane * 8;
      const _Float16* bpb = WSb + (size_t)(kc * 8) * 512 + lane * 8;
#pragma unroll
      for (int nt = 0; nt < 8; nt++) {
        half8 ba = *(const half8*)(bpa + nt * 512);
        half8 bbq = *(const half8*)(bpb + nt * 512);
        as_[nt] = __builtin_amdgcn_mfma_f32_16x16x32_f16(a, ba, as_[nt], 0, 0, 0);
        ad[nt] = __builtin_amdgcn_mfma_f32_16x16x32_f16(a, bbq, ad[nt], 0, 0, 0);
      }
    }
    float bfv[8];
    for (int nt = 0; nt < 8; nt++) bfv[nt] = b1f[nt * 16 + l15];
    for (int reg = 0; reg < 4; reg++) {
      long n = nb0 + quad * 4 + reg;
      if (n < NN) {
        half8 hsv, hdv;
        for (int nt = 0; nt < 8; nt++) {
          hsv[nt] = (_Float16)as_[nt][reg];
          hdv[nt] = (_Float16)(ad[nt][reg] + bfv[nt]);
        }
        *(half8*)(Sh + n * 128 + l15 * 8) = hsv;
        *(half8*)(Dh + n * 128 + l15 * 8) = hdv;
      }
    }
  }
}

// ---------------------------------------------------------------------------
// Message kernel v14 (R8 exact): 2-wave blocks (64 edges) at (128, 3).
// R7/R9 both proved this structure's true liveness is ~136 unified regs:
// any 128-reg cap spills 43-64B/thread (WRITE 18->87MB). (128,3)'s 170
// budget is spill-free; 3 waves/SIMD is this structure's occupancy ceiling.
// Spill falsifier: WRITE_SIZE must be 18.4MB.
// ---------------------------------------------------------------------------
__global__ __launch_bounds__(128, 3) void msg_kernel(
    const _Float16* __restrict__ Sh, const _Float16* __restrict__ Dh,
    const _Float16* __restrict__ efh, const int2* __restrict__ meta,
    const float* __restrict__ cong,
    const _Float16* __restrict__ Wcp, const _Float16* __restrict__ Wp2,
    const _Float16* __restrict__ w1cp, const float* __restrict__ b2,
    __half* __restrict__ agg) {
  __shared__ __align__(16) _Float16 As[64][136];  // h-tile then m-tile
  __shared__ int s_src[64], s_dst[64];
  __shared__ float s_cg[64];
  int t = threadIdx.x, wave = t >> 6, lane = t & 63;
  int quad = lane >> 4, l15 = lane & 15;
  long eb0 = (long)blockIdx.x * 64;
  int web = wave * 32;

  if (t < 64) {
    int2 m = meta[eb0 + t];
    s_src[t] = m.x;
    s_dst[t] = m.y;
    s_cg[t] = cong[m.x];  // 200KB array: L2-resident gather
  }
  // streaming loads independent of meta: issue before the barrier
  half8 wcl = *(const half8*)(w1cp + l15 * 8);
  half8 av0 = *(const half8*)(efh + (size_t)(eb0 + web + l15) * 32 + quad * 8);
  half8 av1 = *(const half8*)(efh + (size_t)(eb0 + web + 16 + l15) * 32 + quad * 8);
  __syncthreads();

  // hoist ALL 16 random gathers: deep MLP across both MFMA clusters
  half8 sv[8], dv[8];
#pragma unroll
  for (int mtl = 0; mtl < 2; mtl++)
#pragma unroll
    for (int reg = 0; reg < 4; reg++) {
      int r = web + mtl * 16 + quad * 4 + reg;
      sv[mtl * 4 + reg] = *(const half8*)(Sh + (size_t)s_src[r] * 128 + l15 * 8);
      dv[mtl * 4 + reg] = *(const half8*)(Dh + (size_t)s_dst[r] * 128 + l15 * 8);
    }

  // Phase E: per wave, 2 M-tiles of 16 edges; packed-fp16 combine
#pragma unroll
  for (int mtl = 0; mtl < 2; mtl++) {
    half8 a = mtl ? av1 : av0;
    floatx4 e[8] = {};
#pragma unroll
    for (int nt = 0; nt < 8; nt++) {
      half8 b = *(const half8*)(Wcp + (size_t)nt * 512 + lane * 8);
      e[nt] = __builtin_amdgcn_mfma_f32_16x16x32_f16(a, b, e[nt], 0, 0, 0);
    }
#pragma unroll
    for (int reg = 0; reg < 4; reg++) {
      int r = web + mtl * 16 + quad * 4 + reg;
      _Float16 cgh = (_Float16)s_cg[r];
      half8 v = sv[mtl * 4 + reg] + dv[mtl * 4 + reg];  // v_pk_add_f16
      half8 e8;
#pragma unroll
      for (int i = 0; i < 4; i++) {
        fp16x2 p = __builtin_amdgcn_cvt_pkrtz(e[2 * i][reg], e[2 * i + 1][reg]);
        e8[2 * i] = (_Float16)p[0];
        e8[2 * i + 1] = (_Float16)p[1];
      }
      v += e8;
      v += wcl * cgh;  // v_pk_fma_f16 (scalar splat)
#pragma unroll
      for (int i = 0; i < 8; i++) v[i] = v[i] > (_Float16)0 ? v[i] : (_Float16)0;
      *(half8*)&As[r][l15 * 8] = v;
    }
  }
  __syncthreads();

  // GEMM2 (N-split): wave owns N-tiles nb..nb+3
  int nb = wave * 4;
  floatx4 acc2[4][4] = {};  // [mt][ntp]
  __builtin_amdgcn_s_setprio(1);
#pragma unroll
  for (int kc = 0; kc < 4; kc++) {
    const _Float16* bp = Wp2 + ((size_t)(kc * 8 + nb)) * 512 + lane * 8;
    half8 b0 = *(const half8*)bp;
    half8 b1v = *(const half8*)(bp + 512);
    half8 b2v = *(const half8*)(bp + 1024);
    half8 b3v = *(const half8*)(bp + 1536);
#pragma unroll
    for (int mt = 0; mt < 4; mt++) {
      half8 a = *(const half8*)&As[mt * 16 + l15][kc * 32 + quad * 8];
      acc2[mt][0] = __builtin_amdgcn_mfma_f32_16x16x32_f16(a, b0, acc2[mt][0], 0, 0, 0);
      acc2[mt][1] = __builtin_amdgcn_mfma_f32_16x16x32_f16(a, b1v, acc2[mt][1], 0, 0, 0);
      acc2[mt][2] = __builtin_amdgcn_mfma_f32_16x16x32_f16(a, b2v, acc2[mt][2], 0, 0, 0);
      acc2[mt][3] = __builtin_amdgcn_mfma_f32_16x16x32_f16(a, b3v, acc2[mt][3], 0, 0, 0);
    }
  }
  __builtin_amdgcn_s_setprio(0);
  __syncthreads();

  // epilogue: bias + direct per-lane b16 stores (all 64 lanes active, no shfl)
  {
    float c[4];
#pragma unroll
    for (int ntp = 0; ntp < 4; ntp++) c[ntp] = b2[(nb + ntp) * 16 + l15];
#pragma unroll
    for (int mt = 0; mt < 4; mt++)
#pragma unroll
      for (int reg = 0; reg < 4; reg++) {
        int row = mt * 16 + quad * 4 + reg;
#pragma unroll
        for (int ntp = 0; ntp < 4; ntp++)
          As[row][(nb + ntp) * 16 + l15] = (_Float16)(acc2[mt][ntp][reg] + c[ntp]);
      }
  }
  __syncthreads();

  // segmented reduction over sorted dst runs (fp16x2 accumulate; agg is fp16
  // RMW-atomic anyway so accumulation precision class is unchanged)
  {
    int cp = lane;
    int r0 = wave * 32;
    __half2 vals[32];
#pragma unroll
    for (int i = 0; i < 32; i++) vals[i] = *(__half2*)&As[r0 + i][cp * 2];
    int cur = s_dst[r0];
    __half2 acc = __float2half2_rn(0.f);
    for (int i = 0; i < 32; i++) {
      int d = s_dst[r0 + i];
      if (d != cur) {
        unsafeAtomicAdd((__half2*)(agg + (long)cur * 128 + cp * 2), acc);
        acc = __float2half2_rn(0.f);
        cur = d;
      }
      acc = __hadd2(acc, vals[i]);
    }
    unsafeAtomicAdd((__half2*)(agg + (long)cur * 128 + cp * 2), acc);
  }
}

// ---------------------------------------------------------------------------
// Update + residual + layernorm (MFMA), with fused SD precompute for the NEXT
// layer (+ agg-slice zeroing). DO_RED is compile-time so layers 0..2 pay no
// register cost for the fused channel-sum.
// ---------------------------------------------------------------------------
template <bool DO_RED>
__global__ __launch_bounds__(256, 3) void upd_kernel(
    _Float16* __restrict__ xh, _Float16* __restrict__ agg,
    const _Float16* __restrict__ Wp1, const _Float16* __restrict__ Wp2,
    const float* __restrict__ b1, const float* __restrict__ b2,
    const float* __restrict__ g, const float* __restrict__ bb,
    const _Float16* __restrict__ WSa, const _Float16* __restrict__ WSb,
    const float* __restrict__ b1f,
    _Float16* __restrict__ Sh, _Float16* __restrict__ Dh,
    float* __restrict__ red) {
  __shared__ __align__(16) _Float16 hs[4][16][136];
  int t = threadIdx.x, wave = t >> 6, lane = t & 63;
  int quad = lane >> 4, l15 = lane & 15;
  long nb0 = (long)blockIdx.x * 64 + wave * 16;

  floatx4 acc[8] = {};
  {
    long n = nb0 + l15;
    long rn = n < NN ? n : NN - 1;
    for (int kc = 0; kc < 8; kc++) {
      half8 a;
      if (kc < 4) {
        a = *(const half8*)(xh + rn * 128 + kc * 32 + quad * 8);
      } else {
        a = *(const half8*)(agg + rn * 128 + (kc - 4) * 32 + quad * 8);
      }
      const _Float16* bp = Wp1 + (size_t)(kc * 8) * 512 + lane * 8;
      for (int nt = 0; nt < 8; nt++) {
        half8 b = *(const half8*)(bp + nt * 512);
        acc[nt] = __builtin_amdgcn_mfma_f32_16x16x32_f16(a, b, acc[nt], 0, 0, 0);
      }
    }
  }

  float bbv[8];
  for (int nt = 0; nt < 8; nt++) bbv[nt] = b1[nt * 16 + l15];
  for (int reg = 0; reg < 4; reg++) {
    half8 hv;
    for (int nt = 0; nt < 8; nt++)
      hv[nt] = (_Float16)fmaxf(acc[nt][reg] + bbv[nt], 0.f);
    *(half8*)&hs[wave][quad * 4 + reg][l15 * 8] = hv;
  }
  __syncthreads();

  floatx4 acc2[8] = {};
  for (int kc = 0; kc < 4; kc++) {
    half8 a = *(const half8*)&hs[wave][l15][kc * 32 + quad * 8];
    const _Float16* bp = Wp2 + (size_t)(kc * 8) * 512 + lane * 8;
    for (int nt = 0; nt < 8; nt++) {
      half8 b = *(const half8*)(bp + nt * 512);
      acc2[nt] = __builtin_amdgcn_mfma_f32_16x16x32_f16(a, b, acc2[nt], 0, 0, 0);
    }
  }

  float b2v[8], gv[8], bv[8];
  for (int nt = 0; nt < 8; nt++) {
    int col = nt * 16 + l15;
    b2v[nt] = b2[col]; gv[nt] = g[col]; bv[nt] = bb[col];
  }
  bool fuse = (WSa != nullptr);
  float cs[DO_RED ? 8 : 1];
  if (DO_RED)
    for (int nt = 0; nt < (DO_RED ? 8 : 1); nt++) cs[nt] = 0.f;
  for (int reg = 0; reg < 4; reg++) {
    long n = nb0 + quad * 4 + reg;
    bool ok = n < NN;
    long rn = ok ? n : NN - 1;
    float y[8];
    float s = 0.f;
    for (int nt = 0; nt < 8; nt++) {
      y[nt] = (float)xh[rn * 128 + nt * 16 + l15] + acc2[nt][reg] + b2v[nt];
      s += y[nt];
    }
    s += __shfl_xor(s, 1); s += __shfl_xor(s, 2);
    s += __shfl_xor(s, 4); s += __shfl_xor(s, 8);
    float mu = s * (1.f / 128.f);
    float q = 0.f;
    for (int nt = 0; nt < 8; nt++) {
      y[nt] -= mu;
      q += y[nt] * y[nt];
    }
    q += __shfl_xor(q, 1); q += __shfl_xor(q, 2);
    q += __shfl_xor(q, 4); q += __shfl_xor(q, 8);
    float rstd = rsqrtf(q * (1.f / 128.f) + 1e-5f);
    for (int nt = 0; nt < 8; nt++) {
      _Float16 o = (_Float16)(y[nt] * rstd * gv[nt] + bv[nt]);
      if (ok) xh[n * 128 + nt * 16 + l15] = o;
      if (fuse) hs[wave][quad * 4 + reg][nt * 16 + l15] = o;  // row layout
      if (DO_RED) cs[nt] += ok ? (float)o : 0.f;
    }
  }

  // fused SD for the next layer (per-wave private LDS slice; same-wave
  // ds_write->ds_read ordering handled by compiler-inserted lgkmcnt)
  if (fuse) {
    floatx4 as_[8] = {}, ad[8] = {};
#pragma unroll
    for (int kc = 0; kc < 4; kc++) {
      half8 a = *(const half8*)&hs[wave][l15][kc * 32 + quad * 8];
      const _Float16* bpa = WSa + (size_t)(kc * 8) * 512 + lane * 8;
      const _Float16* bpb = WSb + (size_t)(kc * 8) * 512 + lane * 8;
#pragma unroll
      for (int nt = 0; nt < 8; nt++) {
        half8 ba = *(const half8*)(bpa + nt * 512);
        half8 bbq = *(const half8*)(bpb + nt * 512);
        as_[nt] = __builtin_amdgcn_mfma_f32_16x16x32_f16(a, ba, as_[nt], 0, 0, 0);
        ad[nt] = __builtin_amdgcn_mfma_f32_16x16x32_f16(a, bbq, ad[nt], 0, 0, 0);
      }
    }
    float bfv[8];
    for (int nt = 0; nt < 8; nt++) bfv[nt] = b1f[nt * 16 + l15];
    for (int reg = 0; reg < 4; reg++) {
      long n = nb0 + quad * 4 + reg;
      if (n < NN) {
        half8 hsv, hdv;
        for (int nt = 0; nt < 8; nt++) {
          hsv[nt] = (_Float16)as_[nt][reg];
          hdv[nt] = (_Float16)(ad[nt][reg] + bfv[nt]);
        }
        *(half8*)(Sh + n * 128 + l15 * 8) = hsv;
        *(half8*)(Dh + n * 128 + l15 * 8) = hdv;
      }
    }

    // zero agg slice for the next msg pass (all reads of agg done above;
    // only this block's lanes ever touch these rows -> race-free)
    long zn = (long)blockIdx.x * 64 + (t >> 2);
    if (zn < NN) {
      float4* p = (float4*)(agg + (long)blockIdx.x * 64 * 128 + t * 32);
      float4 z = {};
      p[0] = z; p[1] = z; p[2] = z; p[3] = z;
    }
  }

  // fused channel-sum on the last layer: block-reduce via hs, 128 atomics
  if (DO_RED) {
    for (int nt = 0; nt < 8; nt++) {
      cs[nt] += __shfl_xor(cs[nt], 16);
      cs[nt] += __shfl_xor(cs[nt], 32);
    }
    __syncthreads();  // all hs reads done (fuse==false on last layer)
    float* hsF = (float*)hs;
    if (quad == 0)
      for (int nt = 0; nt < 8; nt++) hsF[wave * 128 + nt * 16 + l15] = cs[nt];
    __syncthreads();
    if (t < 128)
      atomicAdd(&red[t], hsF[t] + hsF[128 + t] + hsF[256 + t] + hsF[384 + t]);
  }
}

// ---------------------------------------------------------------------------
// Readout head.
// ---------------------------------------------------------------------------
__global__ void readout_kernel(const float* __restrict__ red,
                               const float* __restrict__ xw1, const float* __restrict__ xb1,
                               const float* __restrict__ xw2, const float* __restrict__ xb2,
                               const float* __restrict__ rw1, const float* __restrict__ rb1,
                               const float* __restrict__ rw2, const float* __restrict__ rb2,
                               const float* __restrict__ rw3, const float* __restrict__ rb3,
                               float* __restrict__ out) {
  __shared__ float sa[128], sb[128], sc[128];
  int j = threadIdx.x;
  const float inv = 1.f / (float)NN;
  float ge = red[j] * inv;
  float uf = red[128] * inv;
  float u1 = fmaxf(uf * xw1[j] + xb1[j], 0.f);
  sa[j] = u1;
  sb[j] = ge;
  __syncthreads();
  float u2 = xb2[j];
  for (int k = 0; k < 128; k++) u2 += sa[k] * xw2[k * 128 + j];
  sc[j] = u2;
  __syncthreads();
  float h1 = rb1[j];
  for (int k = 0; k < 128; k++) h1 += sb[k] * rw1[k * 128 + j];
  for (int k = 0; k < 128; k++) h1 += sc[k] * rw1[(128 + k) * 128 + j];
  h1 = fmaxf(h1, 0.f);
  __syncthreads();
  sa[j] = h1;
  __syncthreads();
  float h2 = 0.f;
  if (j < 64) {
    h2 = rb2[j];
    for (int k = 0; k < 128; k++) h2 += sa[k] * rw2[k * 64 + j];
    h2 = fmaxf(h2, 0.f);
  }
  __syncthreads();
  if (j < 64) sb[j] = h2;
  __syncthreads();
  if (j == 0) {
    float a = rb3[0];
    for (int k = 0; k < 64; k++) a += sb[k] * rw3[k];
    out[0] = 1.f / (1.f + expf(-a));
  }
}

// ---------------------------------------------------------------------------
extern "C" void kernel_launch(void* const* d_in, const int* in_sizes, int n_in,
                              void* d_out, int out_size, void* d_ws, size_t ws_size,
                              hipStream_t stream) {
  const float* nf   = (const float*)d_in[0];
  const float* ef   = (const float*)d_in[1];
  const float* cong = (const float*)d_in[2];
  const int*   eidx = (const int*)d_in[3];
  const int*   um   = (const int*)d_in[4];
  const float* enw  = (const float*)d_in[5];
  const float* enb  = (const float*)d_in[6];
  const float* eew  = (const float*)d_in[7];
  const float* eeb  = (const float*)d_in[8];
  const float* mw1  = (const float*)d_in[9];
  const float* mb1  = (const float*)d_in[10];
  const float* mw2  = (const float*)d_in[11];
  const float* mb2  = (const float*)d_in[12];
  const float* uw1  = (const float*)d_in[13];
  const float* ub1  = (const float*)d_in[14];
  const float* uw2  = (const float*)d_in[15];
  const float* ub2  = (const float*)d_in[16];
  const float* lnw  = (const float*)d_in[17];
  const float* lnb  = (const float*)d_in[18];
  const float* xw1  = (const float*)d_in[19];
  const float* xb1  = (const float*)d_in[20];
  const float* xw2  = (const float*)d_in[21];
  const float* xb2  = (const float*)d_in[22];
  const float* rw1  = (const float*)d_in[23];
  const float* rb1  = (const float*)d_in[24];
  const float* rw2  = (const float*)d_in[25];
  const float* rb2  = (const float*)d_in[26];
  const float* rw3  = (const float*)d_in[27];
  const float* rb3  = (const float*)d_in[28];
  float* out = (float*)d_out;

  char* W = (char*)d_ws;
  _Float16* xh    = (_Float16*)(W + 0);          // 12,800,000
  __half*   agg   = (__half*)(W + 12800000);     // 12,800,000
  _Float16* efh   = (_Float16*)(W + 25600000);   // 51,200,000
  _Float16* Sh    = (_Float16*)(W + 76800000);   // 12,800,000
  _Float16* Dh    = (_Float16*)(W + 89600000);   // 12,800,000
  int2*     meta  = (int2*)(W + 102400000);      // 6,400,000
  int*      einv  = (int*)(W + 108800000);       // 3,200,000
  int*      counts= (int*)(W + 112000000);       // 200,000
  int*      offs  = (int*)(W + 112400000);       // 200,000
  _Float16* WSa   = (_Float16*)(W + 112600000);  // 131,072
  _Float16* WSb   = (_Float16*)(W + 112731072);  // 131,072
  _Float16* Wcp   = (_Float16*)(W + 112862144);  // 32,768
  _Float16* Wm2   = (_Float16*)(W + 112894912);  // 131,072
  _Float16* Wu1   = (_Float16*)(W + 113025984);  // 262,144
  _Float16* Wu2   = (_Float16*)(W + 113288128);  // 131,072
  _Float16* Wen   = (_Float16*)(W + 113419200);  // 16,384
  float*    Wc    = (float*)(W + 113435584);     // 65,536
  float*    b1f   = (float*)(W + 113501120);     // 2,048
  _Float16* w1cp  = (_Float16*)(W + 113503168);  // 1,024
  float*    red   = (float*)(W + 113504192);     // 516
  // rank (EE ints = 3.2MB) aliases meta: rank is written by hist and read by
  // slot1; meta is written by slot2 strictly after slot1 completes
  // (stream-ordered). Lifetimes disjoint.
  int*      rank  = (int*)meta;
  // bsum (49 ints = 196B) aliases red: bsum's last reader is slot1; red is
  // memset just before enc and used from enc onward. Lifetimes disjoint.
  int*      bsum  = (int*)red;

  const int* srcv = eidx;
  const int* dstv = eidx + EE;

  // CSR build: hist (stores intra-bucket rank) -> 2-level scan ->
  // atomic-free einv scatter -> coalesced position-order gather
  (void)hipMemsetAsync(counts, 0, 200000, stream);
  hist_kernel<<<3125, 256, 0, stream>>>(dstv, counts, rank);
  scan1_kernel<<<49, 1024, 0, stream>>>(counts, offs, bsum);
  scan2_kernel<<<1, 64, 0, stream>>>(bsum);
  slot1_kernel<<<3125, 256, 0, stream>>>(dstv, offs, bsum, rank, einv);
  slot2_kernel<<<3125, 256, 0, stream>>>(einv, srcv, dstv, ef, meta, efh);

  // weight prep + encoder (enc fuses SD for layer 0 + agg zero + umask count)
  fold_kernel<<<dim3(33, 4), 128, 0, stream>>>(eew, eeb, mw1, mb1, Wc, b1f);
  prep_w<<<dim3(8, 4), 64, 0, stream>>>(Wc, Wcp, 32, 0);
  prep_w<<<dim3(32, 4), 64, 0, stream>>>(mw1, WSa, 385, 0);
  prep_w<<<dim3(32, 4), 64, 0, stream>>>(mw1 + 128 * 128, WSb, 385, 0);
  prep_w<<<dim3(32, 4), 64, 0, stream>>>(mw2, Wm2, 128, 1);
  prep_w<<<dim3(64, 4), 64, 0, stream>>>(uw1, Wu1, 256, 0);
  prep_w<<<dim3(32, 4), 64, 0, stream>>>(uw2, Wu2, 128, 1);
  prep_w<<<dim3(16, 1), 64, 0, stream>>>(enw, Wen, 64, 0);
  prep_cong<<<4, 128, 0, stream>>>(mw1, w1cp);
  // red memset AFTER slot1 (bsum alias) and BEFORE enc (umask accumulation)
  (void)hipMemsetAsync(red, 0, 129 * sizeof(float), stream);
  enc_mfma<<<782, 256, 0, stream>>>(nf, Wen, enb, xh, WSa, WSb, b1f, Sh, Dh,
                                    (_Float16*)agg, um, red);

  for (int l = 0; l < 4; l++) {
    msg_kernel<<<12500, 128, 0, stream>>>(
        Sh, Dh, efh, meta, cong,
        Wcp + (size_t)l * 8 * 512, Wm2 + (size_t)l * 32 * 512,
        w1cp + l * 128, mb2 + l * 128, agg);
    if (l < 3) {
      upd_kernel<false><<<782, 256, 0, stream>>>(
          xh, (_Float16*)agg,
          Wu1 + (size_t)l * 64 * 512, Wu2 + (size_t)l * 32 * 512,
          ub1 + l * 128, ub2 + l * 128, lnw + l * 128, lnb + l * 128,
          WSa + (size_t)(l + 1) * 32 * 512, WSb + (size_t)(l + 1) * 32 * 512,
          b1f + (l + 1) * 128, Sh, Dh, red);
    } else {
      upd_kernel<true><<<782, 256, 0, stream>>>(
          xh, (_Float16*)agg,
          Wu1 + (size_t)l * 64 * 512, Wu2 + (size_t)l * 32 * 512,
          ub1 + l * 128, ub2 + l * 128, lnw + l * 128, lnb + l * 128,
          (const _Float16*)nullptr, (const _Float16*)nullptr,
          (const float*)nullptr, Sh, Dh, red);
    }
  }

  readout_kernel<<<1, 128, 0, stream>>>(red, xw1, xb1, xw2, xb2,
                                        rw1, rb1, rw2, rb2, rw3, rb3, out);
}

// Round 12
// 783.204 us; speedup vs baseline: 1.0884x; 1.0260x over previous
//
#include <hip/hip_runtime.h>
#include <hip/hip_fp16.h>
#include <math.h>

#define NN 50000
#define EE 800000

typedef _Float16 half8 __attribute__((ext_vector_type(8)));
typedef __fp16 fp16x2 __attribute__((ext_vector_type(2)));
typedef float floatx4 __attribute__((ext_vector_type(4)));

// ---------------------------------------------------------------------------
// Fold edge-encoder into msg_w1: Wc[l][c][j], b1f[l][j].
// ---------------------------------------------------------------------------
__global__ void fold_kernel(const float* __restrict__ ew, const float* __restrict__ eb,
                            const float* __restrict__ w1, const float* __restrict__ b1,
                            float* __restrict__ Wc, float* __restrict__ b1f) {
  int l = blockIdx.y, c = blockIdx.x, j = threadIdx.x;
  __shared__ float row[128];
  const float* w1l = w1 + (size_t)l * 385 * 128;
  if (c < 32) {
    row[j] = ew[c * 128 + j];
    __syncthreads();
    float acc = 0.f;
    for (int k = 0; k < 128; k++) acc += row[k] * w1l[(256 + k) * 128 + j];
    Wc[((size_t)l * 32 + c) * 128 + j] = acc;
  } else {
    row[j] = eb[j];
    __syncthreads();
    float acc = b1[l * 128 + j];
    for (int k = 0; k < 128; k++) acc += row[k] * w1l[(256 + k) * 128 + j];
    b1f[l * 128 + j] = acc;
  }
}

// ---------------------------------------------------------------------------
// Merged weight packing: one launch replaces 8x prep_w + prep_cong.
// Segment dispatch on blockIdx.x; per-segment logic identical to the old
// prep_w (fp16 MFMA B-fragment order, perm=1 bakes GEMM2 k-permutation).
// ---------------------------------------------------------------------------
__device__ __forceinline__ void prep_body(const float* __restrict__ src,
                                          _Float16* __restrict__ dst,
                                          int K, int perm, int gx, int l,
                                          int bx, int lane) {
  int kc = bx >> 3, nt = bx & 7;
  int n = nt * 16 + (lane & 15);
  int k0 = kc * 32 + (lane >> 4) * 8;
  const float* s = src + (size_t)l * K * 128;
  _Float16 out[8];
  for (int j = 0; j < 8; j++) {
    int k = k0 + j;
    int ks = perm ? ((k & 7) * 16 + (k >> 3)) : k;
    out[j] = (_Float16)s[(size_t)ks * 128 + n];
  }
  _Float16* d = dst + (((size_t)l * gx + bx) * 64 + lane) * 8;
  *(half8*)d = *(half8*)out;
}

__global__ void prep_all(const float* __restrict__ mw1, const float* __restrict__ mw2,
                         const float* __restrict__ uw1, const float* __restrict__ uw2,
                         const float* __restrict__ enw, const float* __restrict__ Wc,
                         _Float16* __restrict__ WSa, _Float16* __restrict__ WSb,
                         _Float16* __restrict__ Wm2, _Float16* __restrict__ Wu1,
                         _Float16* __restrict__ Wu2, _Float16* __restrict__ Wcp,
                         _Float16* __restrict__ Wen, _Float16* __restrict__ w1cp) {
  int b = blockIdx.x, lane = threadIdx.x;
  if (b < 128) {
    prep_body(mw1, WSa, 385, 0, 32, b >> 5, b & 31, lane);
  } else if (b < 256) {
    b -= 128; prep_body(mw1 + 128 * 128, WSb, 385, 0, 32, b >> 5, b & 31, lane);
  } else if (b < 384) {
    b -= 256; prep_body(mw2, Wm2, 128, 1, 32, b >> 5, b & 31, lane);
  } else if (b < 640) {
    b -= 384; prep_body(uw1, Wu1, 256, 0, 64, b >> 6, b & 63, lane);
  } else if (b < 768) {
    b -= 640; prep_body(uw2, Wu2, 128, 1, 32, b >> 5, b & 31, lane);
  } else if (b < 800) {
    b -= 768; prep_body(Wc, Wcp, 32, 0, 8, b >> 3, b & 7, lane);
  } else if (b < 816) {
    b -= 800; prep_body(enw, Wen, 64, 0, 16, 0, b, lane);
  } else {
    int l = b - 816;  // congestion column (mw1 row 384), k-perm layout
    for (int h = 0; h < 2; h++) {
      int p = lane + h * 64;
      int col = (p & 7) * 16 + (p >> 3);
      w1cp[l * 128 + p] = (_Float16)mw1[((size_t)l * 385 + 384) * 128 + col];
    }
  }
}

// ---------------------------------------------------------------------------
// CSR build: histogram (storing each edge's intra-bucket rank from the
// returned atomic counter), parallel 2-level scan, ATOMIC-FREE einv scatter,
// then the coalesced position-order gather pass.
// ---------------------------------------------------------------------------
__global__ void hist_kernel(const int* __restrict__ dstv, int* __restrict__ counts,
                            int* __restrict__ rank) {
  int e = blockIdx.x * 256 + threadIdx.x;
  if (e < EE) rank[e] = atomicAdd(&counts[dstv[e]], 1);
}

// per-block exclusive scan of 1024 counts + block totals
__global__ void scan1_kernel(const int* __restrict__ counts, int* __restrict__ offs,
                             int* __restrict__ bsum) {
  __shared__ int ws[16];
  int t = threadIdx.x, lane = t & 63, w = t >> 6;
  int i = blockIdx.x * 1024 + t;
  int v = (i < NN) ? counts[i] : 0;
  int s = v;
  for (int off = 1; off < 64; off <<= 1) {
    int u = __shfl_up(s, off);
    if (lane >= off) s += u;
  }
  if (lane == 63) ws[w] = s;
  __syncthreads();
  if (w == 0) {
    int u = (lane < 16) ? ws[lane] : 0;
    for (int off = 1; off < 16; off <<= 1) {
      int x = __shfl_up(u, off);
      if (lane >= off && lane < 16) u += x;
    }
    if (lane < 16) ws[lane] = u;
  }
  __syncthreads();
  int wbase = (w > 0) ? ws[w - 1] : 0;
  if (i < NN) offs[i] = wbase + s - v;
  if (t == 0) bsum[blockIdx.x] = ws[15];
}

// single-wave exclusive scan of the 49 block totals, in place
__global__ void scan2_kernel(int* __restrict__ bsum) {
  int t = threadIdx.x;
  int v = (t < 49) ? bsum[t] : 0;
  int s = v;
  for (int off = 1; off < 64; off <<= 1) {
    int u = __shfl_up(s, off);
    if (t >= off) s += u;
  }
  if (t < 49) bsum[t] = s - v;
}

// atomic-free inverse permutation: p = offs[d] + bsum-chunk + rank[e]
__global__ void slot1_kernel(const int* __restrict__ dstv, const int* __restrict__ offs,
                             const int* __restrict__ bsum, const int* __restrict__ rank,
                             int* __restrict__ einv) {
  int e = blockIdx.x * 256 + threadIdx.x;
  if (e >= EE) return;
  int d = dstv[e];
  int p = offs[d] + bsum[d >> 10] + rank[e];
  einv[p] = e;
}

// position-order pass, 2 edges/thread for deeper memory-level parallelism:
// all random full-line reads issue before any conversion; writes coalesced.
__global__ void slot2_kernel(const int* __restrict__ einv, const int* __restrict__ srcv,
                             const int* __restrict__ dstv, const float* __restrict__ ef,
                             int2* __restrict__ meta, _Float16* __restrict__ efh) {
  int p0 = blockIdx.x * 512 + threadIdx.x;
  int p1 = p0 + 256;
  bool v0 = p0 < EE, v1 = p1 < EE;
  int e0 = v0 ? einv[p0] : 0;
  int e1 = v1 ? einv[p1] : 0;
  int s0 = v0 ? srcv[e0] : 0, d0 = v0 ? dstv[e0] : 0;
  int s1 = v1 ? srcv[e1] : 0, d1 = v1 ? dstv[e1] : 0;
  const float* sp0 = ef + (size_t)e0 * 32;
  const float* sp1 = ef + (size_t)e1 * 32;
  float4 f0[8], f1[8];
#pragma unroll
  for (int i = 0; i < 8; i++) f0[i] = *(const float4*)(sp0 + i * 4);
#pragma unroll
  for (int i = 0; i < 8; i++) f1[i] = *(const float4*)(sp1 + i * 4);
  if (v0) {
    int2 m; m.x = s0; m.y = d0;
    meta[p0] = m;
    _Float16* dp = efh + (size_t)p0 * 32;
#pragma unroll
    for (int i = 0; i < 4; i++) {
      half8 v;
      v[0] = (_Float16)f0[2*i].x; v[1] = (_Float16)f0[2*i].y;
      v[2] = (_Float16)f0[2*i].z; v[3] = (_Float16)f0[2*i].w;
      v[4] = (_Float16)f0[2*i+1].x; v[5] = (_Float16)f0[2*i+1].y;
      v[6] = (_Float16)f0[2*i+1].z; v[7] = (_Float16)f0[2*i+1].w;
      *(half8*)(dp + i * 8) = v;
    }
  }
  if (v1) {
    int2 m; m.x = s1; m.y = d1;
    meta[p1] = m;
    _Float16* dp = efh + (size_t)p1 * 32;
#pragma unroll
    for (int i = 0; i < 4; i++) {
      half8 v;
      v[0] = (_Float16)f1[2*i].x; v[1] = (_Float16)f1[2*i].y;
      v[2] = (_Float16)f1[2*i].z; v[3] = (_Float16)f1[2*i].w;
      v[4] = (_Float16)f1[2*i+1].x; v[5] = (_Float16)f1[2*i+1].y;
      v[6] = (_Float16)f1[2*i+1].z; v[7] = (_Float16)f1[2*i+1].w;
      *(half8*)(dp + i * 8) = v;
    }
  }
}

// ---------------------------------------------------------------------------
// Node encoder via MFMA (writes fp16 xh) + fused SD precompute for layer 0.
// Also zeroes this block's agg slice (replaces the layer-0 memset) and
// accumulates the unrouted-mask count into red[128].
// ---------------------------------------------------------------------------
__global__ void enc_mfma(const float* __restrict__ nf, const _Float16* __restrict__ Wenc,
                         const float* __restrict__ bn, _Float16* __restrict__ xh,
                         const _Float16* __restrict__ WSa, const _Float16* __restrict__ WSb,
                         const float* __restrict__ b1f,
                         _Float16* __restrict__ Sh, _Float16* __restrict__ Dh,
                         _Float16* __restrict__ aggz,
                         const int* __restrict__ um, float* __restrict__ red) {
  __shared__ __align__(16) _Float16 hs[4][16][136];
  int t = threadIdx.x, wave = t >> 6, lane = t & 63;
  int quad = lane >> 4, l15 = lane & 15;
  long nb0 = (long)blockIdx.x * 64 + wave * 16;
  long rn = nb0 + l15;
  if (rn >= NN) rn = NN - 1;

  // zero agg slice (64 rows x 256B = 16KB; 64B/thread, coalesced)
  {
    long zn = (long)blockIdx.x * 64 + (t >> 2);
    if (zn < NN) {
      float4* p = (float4*)(aggz + (long)blockIdx.x * 64 * 128 + t * 32);
      float4 z = {};
      p[0] = z; p[1] = z; p[2] = z; p[3] = z;
    }
  }

  // umask partial count (wave 0 only; one atomic per block)
  if (t < 64) {
    long n = (long)blockIdx.x * 64 + t;
    float mv = (n < NN) ? (float)um[n] : 0.f;
    for (int off = 32; off; off >>= 1) mv += __shfl_xor(mv, off);
    if (t == 0) atomicAdd(&red[128], mv);
  }

  floatx4 acc[8] = {};
  for (int kc = 0; kc < 2; kc++) {
    const float* p = nf + rn * 64 + kc * 32 + quad * 8;
    float4 f0 = *(const float4*)p;
    float4 f1 = *(const float4*)(p + 4);
    half8 a;
    a[0] = (_Float16)f0.x; a[1] = (_Float16)f0.y;
    a[2] = (_Float16)f0.z; a[3] = (_Float16)f0.w;
    a[4] = (_Float16)f1.x; a[5] = (_Float16)f1.y;
    a[6] = (_Float16)f1.z; a[7] = (_Float16)f1.w;
    const _Float16* bp = Wenc + (size_t)(kc * 8) * 512 + lane * 8;
    for (int nt = 0; nt < 8; nt++) {
      half8 b = *(const half8*)(bp + nt * 512);
      acc[nt] = __builtin_amdgcn_mfma_f32_16x16x32_f16(a, b, acc[nt], 0, 0, 0);
    }
  }
  float bv[8];
  for (int nt = 0; nt < 8; nt++) bv[nt] = bn[nt * 16 + l15];
  for (int reg = 0; reg < 4; reg++) {
    long n = nb0 + quad * 4 + reg;
    bool ok = n < NN;
    for (int nt = 0; nt < 8; nt++) {
      _Float16 v = (_Float16)(acc[nt][reg] + bv[nt]);
      if (ok) xh[n * 128 + nt * 16 + l15] = v;
      hs[wave][quad * 4 + reg][nt * 16 + l15] = v;  // row layout for fused SD
    }
  }

  // fused SD (layer 0): per-wave private LDS slice, same-wave ds ordering
  {
    floatx4 as_[8] = {}, ad[8] = {};
#pragma unroll
    for (int kc = 0; kc < 4; kc++) {
      half8 a = *(const half8*)&hs[wave][l15][kc * 32 + quad * 8];
      const _Float16* bpa = WSa + (size_t)(kc * 8) * 512 + lane * 8;
      const _Float16* bpb = WSb + (size_t)(kc * 8) * 512 + lane * 8;
#pragma unroll
      for (int nt = 0; nt < 8; nt++) {
        half8 ba = *(const half8*)(bpa + nt * 512);
        half8 bbq = *(const half8*)(bpb + nt * 512);
        as_[nt] = __builtin_amdgcn_mfma_f32_16x16x32_f16(a, ba, as_[nt], 0, 0, 0);
        ad[nt] = __builtin_amdgcn_mfma_f32_16x16x32_f16(a, bbq, ad[nt], 0, 0, 0);
      }
    }
    float bfv[8];
    for (int nt = 0; nt < 8; nt++) bfv[nt] = b1f[nt * 16 + l15];
    for (int reg = 0; reg < 4; reg++) {
      long n = nb0 + quad * 4 + reg;
      if (n < NN) {
        half8 hsv, hdv;
        for (int nt = 0; nt < 8; nt++) {
          hsv[nt] = (_Float16)as_[nt][reg];
          hdv[nt] = (_Float16)(ad[nt][reg] + bfv[nt]);
        }
        *(half8*)(Sh + n * 128 + l15 * 8) = hsv;
        *(half8*)(Dh + n * 128 + l15 * 8) = hdv;
      }
    }
  }
}

// ---------------------------------------------------------------------------
// Message kernel v14 (R8 exact): 2-wave blocks (64 edges) at (128, 3).
// R7/R9 both proved this structure's true liveness is ~136 unified regs:
// any 128-reg cap spills 43-64B/thread (WRITE 18->87MB). (128,3)'s 170
// budget is spill-free; 3 waves/SIMD is this structure's occupancy ceiling.
// Spill falsifier: WRITE_SIZE must be 18.4MB.
// ---------------------------------------------------------------------------
__global__ __launch_bounds__(128, 3) void msg_kernel(
    const _Float16* __restrict__ Sh, const _Float16* __restrict__ Dh,
    const _Float16* __restrict__ efh, const int2* __restrict__ meta,
    const float* __restrict__ cong,
    const _Float16* __restrict__ Wcp, const _Float16* __restrict__ Wp2,
    const _Float16* __restrict__ w1cp, const float* __restrict__ b2,
    __half* __restrict__ agg) {
  __shared__ __align__(16) _Float16 As[64][136];  // h-tile then m-tile
  __shared__ int s_src[64], s_dst[64];
  __shared__ float s_cg[64];
  int t = threadIdx.x, wave = t >> 6, lane = t & 63;
  int quad = lane >> 4, l15 = lane & 15;
  long eb0 = (long)blockIdx.x * 64;
  int web = wave * 32;

  if (t < 64) {
    int2 m = meta[eb0 + t];
    s_src[t] = m.x;
    s_dst[t] = m.y;
    s_cg[t] = cong[m.x];  // 200KB array: L2-resident gather
  }
  // streaming loads independent of meta: issue before the barrier
  half8 wcl = *(const half8*)(w1cp + l15 * 8);
  half8 av0 = *(const half8*)(efh + (size_t)(eb0 + web + l15) * 32 + quad * 8);
  half8 av1 = *(const half8*)(efh + (size_t)(eb0 + web + 16 + l15) * 32 + quad * 8);
  __syncthreads();

  // hoist ALL 16 random gathers: deep MLP across both MFMA clusters
  half8 sv[8], dv[8];
#pragma unroll
  for (int mtl = 0; mtl < 2; mtl++)
#pragma unroll
    for (int reg = 0; reg < 4; reg++) {
      int r = web + mtl * 16 + quad * 4 + reg;
      sv[mtl * 4 + reg] = *(const half8*)(Sh + (size_t)s_src[r] * 128 + l15 * 8);
      dv[mtl * 4 + reg] = *(const half8*)(Dh + (size_t)s_dst[r] * 128 + l15 * 8);
    }

  // Phase E: per wave, 2 M-tiles of 16 edges; packed-fp16 combine
#pragma unroll
  for (int mtl = 0; mtl < 2; mtl++) {
    half8 a = mtl ? av1 : av0;
    floatx4 e[8] = {};
#pragma unroll
    for (int nt = 0; nt < 8; nt++) {
      half8 b = *(const half8*)(Wcp + (size_t)nt * 512 + lane * 8);
      e[nt] = __builtin_amdgcn_mfma_f32_16x16x32_f16(a, b, e[nt], 0, 0, 0);
    }
#pragma unroll
    for (int reg = 0; reg < 4; reg++) {
      int r = web + mtl * 16 + quad * 4 + reg;
      _Float16 cgh = (_Float16)s_cg[r];
      half8 v = sv[mtl * 4 + reg] + dv[mtl * 4 + reg];  // v_pk_add_f16
      half8 e8;
#pragma unroll
      for (int i = 0; i < 4; i++) {
        fp16x2 p = __builtin_amdgcn_cvt_pkrtz(e[2 * i][reg], e[2 * i + 1][reg]);
        e8[2 * i] = (_Float16)p[0];
        e8[2 * i + 1] = (_Float16)p[1];
      }
      v += e8;
      v += wcl * cgh;  // v_pk_fma_f16 (scalar splat)
#pragma unroll
      for (int i = 0; i < 8; i++) v[i] = v[i] > (_Float16)0 ? v[i] : (_Float16)0;
      *(half8*)&As[r][l15 * 8] = v;
    }
  }
  __syncthreads();

  // GEMM2 (N-split): wave owns N-tiles nb..nb+3
  int nb = wave * 4;
  floatx4 acc2[4][4] = {};  // [mt][ntp]
  __builtin_amdgcn_s_setprio(1);
#pragma unroll
  for (int kc = 0; kc < 4; kc++) {
    const _Float16* bp = Wp2 + ((size_t)(kc * 8 + nb)) * 512 + lane * 8;
    half8 b0 = *(const half8*)bp;
    half8 b1v = *(const half8*)(bp + 512);
    half8 b2v = *(const half8*)(bp + 1024);
    half8 b3v = *(const half8*)(bp + 1536);
#pragma unroll
    for (int mt = 0; mt < 4; mt++) {
      half8 a = *(const half8*)&As[mt * 16 + l15][kc * 32 + quad * 8];
      acc2[mt][0] = __builtin_amdgcn_mfma_f32_16x16x32_f16(a, b0, acc2[mt][0], 0, 0, 0);
      acc2[mt][1] = __builtin_amdgcn_mfma_f32_16x16x32_f16(a, b1v, acc2[mt][1], 0, 0, 0);
      acc2[mt][2] = __builtin_amdgcn_mfma_f32_16x16x32_f16(a, b2v, acc2[mt][2], 0, 0, 0);
      acc2[mt][3] = __builtin_amdgcn_mfma_f32_16x16x32_f16(a, b3v, acc2[mt][3], 0, 0, 0);
    }
  }
  __builtin_amdgcn_s_setprio(0);
  __syncthreads();

  // epilogue: bias + direct per-lane b16 stores (all 64 lanes active, no shfl)
  {
    float c[4];
#pragma unroll
    for (int ntp = 0; ntp < 4; ntp++) c[ntp] = b2[(nb + ntp) * 16 + l15];
#pragma unroll
    for (int mt = 0; mt < 4; mt++)
#pragma unroll
      for (int reg = 0; reg < 4; reg++) {
        int row = mt * 16 + quad * 4 + reg;
#pragma unroll
        for (int ntp = 0; ntp < 4; ntp++)
          As[row][(nb + ntp) * 16 + l15] = (_Float16)(acc2[mt][ntp][reg] + c[ntp]);
      }
  }
  __syncthreads();

  // segmented reduction over sorted dst runs (fp16x2 accumulate; agg is fp16
  // RMW-atomic anyway so accumulation precision class is unchanged)
  {
    int cp = lane;
    int r0 = wave * 32;
    __half2 vals[32];
#pragma unroll
    for (int i = 0; i < 32; i++) vals[i] = *(__half2*)&As[r0 + i][cp * 2];
    int cur = s_dst[r0];
    __half2 acc = __float2half2_rn(0.f);
    for (int i = 0; i < 32; i++) {
      int d = s_dst[r0 + i];
      if (d != cur) {
        unsafeAtomicAdd((__half2*)(agg + (long)cur * 128 + cp * 2), acc);
        acc = __float2half2_rn(0.f);
        cur = d;
      }
      acc = __hadd2(acc, vals[i]);
    }
    unsafeAtomicAdd((__half2*)(agg + (long)cur * 128 + cp * 2), acc);
  }
}

// ---------------------------------------------------------------------------
// Update + residual + layernorm (MFMA), with fused SD precompute for the NEXT
// layer (+ agg-slice zeroing). DO_RED is compile-time so layers 0..2 pay no
// register cost for the fused channel-sum. NEW: phase-1's xh tile is stashed
// in wave-private LDS (xs) so the LN residual reads LDS instead of 32 scalar
// 2B global loads/thread (kills a dependent HBM stall chain + 12.8MB/layer).
// ---------------------------------------------------------------------------
template <bool DO_RED>
__global__ __launch_bounds__(256, 3) void upd_kernel(
    _Float16* __restrict__ xh, _Float16* __restrict__ agg,
    const _Float16* __restrict__ Wp1, const _Float16* __restrict__ Wp2,
    const float* __restrict__ b1, const float* __restrict__ b2,
    const float* __restrict__ g, const float* __restrict__ bb,
    const _Float16* __restrict__ WSa, const _Float16* __restrict__ WSb,
    const float* __restrict__ b1f,
    _Float16* __restrict__ Sh, _Float16* __restrict__ Dh,
    float* __restrict__ red) {
  __shared__ __align__(16) _Float16 hs[4][16][136];
  __shared__ __align__(16) _Float16 xs[4][16][136];
  int t = threadIdx.x, wave = t >> 6, lane = t & 63;
  int quad = lane >> 4, l15 = lane & 15;
  long nb0 = (long)blockIdx.x * 64 + wave * 16;

  floatx4 acc[8] = {};
  {
    long n = nb0 + l15;
    long rn = n < NN ? n : NN - 1;
    for (int kc = 0; kc < 8; kc++) {
      half8 a;
      if (kc < 4) {
        a = *(const half8*)(xh + rn * 128 + kc * 32 + quad * 8);
        *(half8*)&xs[wave][l15][kc * 32 + quad * 8] = a;  // stash for residual
      } else {
        a = *(const half8*)(agg + rn * 128 + (kc - 4) * 32 + quad * 8);
      }
      const _Float16* bp = Wp1 + (size_t)(kc * 8) * 512 + lane * 8;
      for (int nt = 0; nt < 8; nt++) {
        half8 b = *(const half8*)(bp + nt * 512);
        acc[nt] = __builtin_amdgcn_mfma_f32_16x16x32_f16(a, b, acc[nt], 0, 0, 0);
      }
    }
  }

  float bbv[8];
  for (int nt = 0; nt < 8; nt++) bbv[nt] = b1[nt * 16 + l15];
  for (int reg = 0; reg < 4; reg++) {
    half8 hv;
    for (int nt = 0; nt < 8; nt++)
      hv[nt] = (_Float16)fmaxf(acc[nt][reg] + bbv[nt], 0.f);
    *(half8*)&hs[wave][quad * 4 + reg][l15 * 8] = hv;
  }
  __syncthreads();

  floatx4 acc2[8] = {};
  for (int kc = 0; kc < 4; kc++) {
    half8 a = *(const half8*)&hs[wave][l15][kc * 32 + quad * 8];
    const _Float16* bp = Wp2 + (size_t)(kc * 8) * 512 + lane * 8;
    for (int nt = 0; nt < 8; nt++) {
      half8 b = *(const half8*)(bp + nt * 512);
      acc2[nt] = __builtin_amdgcn_mfma_f32_16x16x32_f16(a, b, acc2[nt], 0, 0, 0);
    }
  }

  float b2v[8], gv[8], bv[8];
  for (int nt = 0; nt < 8; nt++) {
    int col = nt * 16 + l15;
    b2v[nt] = b2[col]; gv[nt] = g[col]; bv[nt] = bb[col];
  }
  bool fuse = (WSa != nullptr);
  float cs[DO_RED ? 8 : 1];
  if (DO_RED)
    for (int nt = 0; nt < (DO_RED ? 8 : 1); nt++) cs[nt] = 0.f;
  for (int reg = 0; reg < 4; reg++) {
    long n = nb0 + quad * 4 + reg;
    bool ok = n < NN;
    float y[8];
    float s = 0.f;
    for (int nt = 0; nt < 8; nt++) {
      y[nt] = (float)xs[wave][quad * 4 + reg][nt * 16 + l15] +
              acc2[nt][reg] + b2v[nt];
      s += y[nt];
    }
    s += __shfl_xor(s, 1); s += __shfl_xor(s, 2);
    s += __shfl_xor(s, 4); s += __shfl_xor(s, 8);
    float mu = s * (1.f / 128.f);
    float q = 0.f;
    for (int nt = 0; nt < 8; nt++) {
      y[nt] -= mu;
      q += y[nt] * y[nt];
    }
    q += __shfl_xor(q, 1); q += __shfl_xor(q, 2);
    q += __shfl_xor(q, 4); q += __shfl_xor(q, 8);
    float rstd = rsqrtf(q * (1.f / 128.f) + 1e-5f);
    for (int nt = 0; nt < 8; nt++) {
      _Float16 o = (_Float16)(y[nt] * rstd * gv[nt] + bv[nt]);
      if (ok) xh[n * 128 + nt * 16 + l15] = o;
      if (fuse) hs[wave][quad * 4 + reg][nt * 16 + l15] = o;  // row layout
      if (DO_RED) cs[nt] += ok ? (float)o : 0.f;
    }
  }

  // fused SD for the next layer (per-wave private LDS slice; same-wave
  // ds_write->ds_read ordering handled by compiler-inserted lgkmcnt)
  if (fuse) {
    floatx4 as_[8] = {}, ad[8] = {};
#pragma unroll
    for (int kc = 0; kc < 4; kc++) {
      half8 a = *(const half8*)&hs[wave][l15][kc * 32 + quad * 8];
      const _Float16* bpa = WSa + (size_t)(kc * 8) * 512 + lane * 8;
      const _Float16* bpb = WSb + (size_t)(kc * 8) * 512 + lane * 8;
#pragma unroll
      for (int nt = 0; nt < 8; nt++) {
        half8 ba = *(const half8*)(bpa + nt * 512);
        half8 bbq = *(const half8*)(bpb + nt * 512);
        as_[nt] = __builtin_amdgcn_mfma_f32_16x16x32_f16(a, ba, as_[nt], 0, 0, 0);
        ad[nt] = __builtin_amdgcn_mfma_f32_16x16x32_f16(a, bbq, ad[nt], 0, 0, 0);
      }
    }
    float bfv[8];
    for (int nt = 0; nt < 8; nt++) bfv[nt] = b1f[nt * 16 + l15];
    for (int reg = 0; reg < 4; reg++) {
      long n = nb0 + quad * 4 + reg;
      if (n < NN) {
        half8 hsv, hdv;
        for (int nt = 0; nt < 8; nt++) {
          hsv[nt] = (_Float16)as_[nt][reg];
          hdv[nt] = (_Float16)(ad[nt][reg] + bfv[nt]);
        }
        *(half8*)(Sh + n * 128 + l15 * 8) = hsv;
        *(half8*)(Dh + n * 128 + l15 * 8) = hdv;
      }
    }

    // zero agg slice for the next msg pass (all reads of agg done above;
    // only this block's lanes ever touch these rows -> race-free)
    long zn = (long)blockIdx.x * 64 + (t >> 2);
    if (zn < NN) {
      float4* p = (float4*)(agg + (long)blockIdx.x * 64 * 128 + t * 32);
      float4 z = {};
      p[0] = z; p[1] = z; p[2] = z; p[3] = z;
    }
  }

  // fused channel-sum on the last layer: block-reduce via hs, 128 atomics
  if (DO_RED) {
    for (int nt = 0; nt < 8; nt++) {
      cs[nt] += __shfl_xor(cs[nt], 16);
      cs[nt] += __shfl_xor(cs[nt], 32);
    }
    __syncthreads();  // all hs reads done (fuse==false on last layer)
    float* hsF = (float*)hs;
    if (quad == 0)
      for (int nt = 0; nt < 8; nt++) hsF[wave * 128 + nt * 16 + l15] = cs[nt];
    __syncthreads();
    if (t < 128)
      atomicAdd(&red[t], hsF[t] + hsF[128 + t] + hsF[256 + t] + hsF[384 + t]);
  }
}

// ---------------------------------------------------------------------------
// Readout head.
// ---------------------------------------------------------------------------
__global__ void readout_kernel(const float* __restrict__ red,
                               const float* __restrict__ xw1, const float* __restrict__ xb1,
                               const float* __restrict__ xw2, const float* __restrict__ xb2,
                               const float* __restrict__ rw1, const float* __restrict__ rb1,
                               const float* __restrict__ rw2, const float* __restrict__ rb2,
                               const float* __restrict__ rw3, const float* __restrict__ rb3,
                               float* __restrict__ out) {
  __shared__ float sa[128], sb[128], sc[128];
  int j = threadIdx.x;
  const float inv = 1.f / (float)NN;
  float ge = red[j] * inv;
  float uf = red[128] * inv;
  float u1 = fmaxf(uf * xw1[j] + xb1[j], 0.f);
  sa[j] = u1;
  sb[j] = ge;
  __syncthreads();
  float u2 = xb2[j];
  for (int k = 0; k < 128; k++) u2 += sa[k] * xw2[k * 128 + j];
  sc[j] = u2;
  __syncthreads();
  float h1 = rb1[j];
  for (int k = 0; k < 128; k++) h1 += sb[k] * rw1[k * 128 + j];
  for (int k = 0; k < 128; k++) h1 += sc[k] * rw1[(128 + k) * 128 + j];
  h1 = fmaxf(h1, 0.f);
  __syncthreads();
  sa[j] = h1;
  __syncthreads();
  float h2 = 0.f;
  if (j < 64) {
    h2 = rb2[j];
    for (int k = 0; k < 128; k++) h2 += sa[k] * rw2[k * 64 + j];
    h2 = fmaxf(h2, 0.f);
  }
  __syncthreads();
  if (j < 64) sb[j] = h2;
  __syncthreads();
  if (j == 0) {
    float a = rb3[0];
    for (int k = 0; k < 64; k++) a += sb[k] * rw3[k];
    out[0] = 1.f / (1.f + expf(-a));
  }
}

// ---------------------------------------------------------------------------
extern "C" void kernel_launch(void* const* d_in, const int* in_sizes, int n_in,
                              void* d_out, int out_size, void* d_ws, size_t ws_size,
                              hipStream_t stream) {
  const float* nf   = (const float*)d_in[0];
  const float* ef   = (const float*)d_in[1];
  const float* cong = (const float*)d_in[2];
  const int*   eidx = (const int*)d_in[3];
  const int*   um   = (const int*)d_in[4];
  const float* enw  = (const float*)d_in[5];
  const float* enb  = (const float*)d_in[6];
  const float* eew  = (const float*)d_in[7];
  const float* eeb  = (const float*)d_in[8];
  const float* mw1  = (const float*)d_in[9];
  const float* mb1  = (const float*)d_in[10];
  const float* mw2  = (const float*)d_in[11];
  const float* mb2  = (const float*)d_in[12];
  const float* uw1  = (const float*)d_in[13];
  const float* ub1  = (const float*)d_in[14];
  const float* uw2  = (const float*)d_in[15];
  const float* ub2  = (const float*)d_in[16];
  const float* lnw  = (const float*)d_in[17];
  const float* lnb  = (const float*)d_in[18];
  const float* xw1  = (const float*)d_in[19];
  const float* xb1  = (const float*)d_in[20];
  const float* xw2  = (const float*)d_in[21];
  const float* xb2  = (const float*)d_in[22];
  const float* rw1  = (const float*)d_in[23];
  const float* rb1  = (const float*)d_in[24];
  const float* rw2  = (const float*)d_in[25];
  const float* rb2  = (const float*)d_in[26];
  const float* rw3  = (const float*)d_in[27];
  const float* rb3  = (const float*)d_in[28];
  float* out = (float*)d_out;

  char* W = (char*)d_ws;
  _Float16* xh    = (_Float16*)(W + 0);          // 12,800,000
  __half*   agg   = (__half*)(W + 12800000);     // 12,800,000
  _Float16* efh   = (_Float16*)(W + 25600000);   // 51,200,000
  _Float16* Sh    = (_Float16*)(W + 76800000);   // 12,800,000
  _Float16* Dh    = (_Float16*)(W + 89600000);   // 12,800,000
  int2*     meta  = (int2*)(W + 102400000);      // 6,400,000
  int*      einv  = (int*)(W + 108800000);       // 3,200,000
  int*      counts= (int*)(W + 112000000);       // 200,000
  int*      offs  = (int*)(W + 112400000);       // 200,000
  _Float16* WSa   = (_Float16*)(W + 112600000);  // 131,072
  _Float16* WSb   = (_Float16*)(W + 112731072);  // 131,072
  _Float16* Wcp   = (_Float16*)(W + 112862144);  // 32,768
  _Float16* Wm2   = (_Float16*)(W + 112894912);  // 131,072
  _Float16* Wu1   = (_Float16*)(W + 113025984);  // 262,144
  _Float16* Wu2   = (_Float16*)(W + 113288128);  // 131,072
  _Float16* Wen   = (_Float16*)(W + 113419200);  // 16,384
  float*    Wc    = (float*)(W + 113435584);     // 65,536
  float*    b1f   = (float*)(W + 113501120);     // 2,048
  _Float16* w1cp  = (_Float16*)(W + 113503168);  // 1,024
  float*    red   = (float*)(W + 113504192);     // 516
  // rank (EE ints = 3.2MB) aliases meta: rank is written by hist and read by
  // slot1; meta is written by slot2 strictly after slot1 completes
  // (stream-ordered). Lifetimes disjoint.
  int*      rank  = (int*)meta;
  // bsum (49 ints = 196B) aliases red: bsum's last reader is slot1; red is
  // memset just before enc and used from enc onward. Lifetimes disjoint.
  int*      bsum  = (int*)red;

  const int* srcv = eidx;
  const int* dstv = eidx + EE;

  // CSR build: hist (stores intra-bucket rank) -> 2-level scan ->
  // atomic-free einv scatter -> coalesced position-order gather (2 edges/thr)
  (void)hipMemsetAsync(counts, 0, 200000, stream);
  hist_kernel<<<3125, 256, 0, stream>>>(dstv, counts, rank);
  scan1_kernel<<<49, 1024, 0, stream>>>(counts, offs, bsum);
  scan2_kernel<<<1, 64, 0, stream>>>(bsum);
  slot1_kernel<<<3125, 256, 0, stream>>>(dstv, offs, bsum, rank, einv);
  slot2_kernel<<<1563, 256, 0, stream>>>(einv, srcv, dstv, ef, meta, efh);

  // weight prep: fold then ONE merged prep launch (was 9 launches)
  fold_kernel<<<dim3(33, 4), 128, 0, stream>>>(eew, eeb, mw1, mb1, Wc, b1f);
  prep_all<<<820, 64, 0, stream>>>(mw1, mw2, uw1, uw2, enw, Wc,
                                   WSa, WSb, Wm2, Wu1, Wu2, Wcp, Wen, w1cp);
  // red memset AFTER slot1 (bsum alias) and BEFORE enc (umask accumulation)
  (void)hipMemsetAsync(red, 0, 129 * sizeof(float), stream);
  enc_mfma<<<782, 256, 0, stream>>>(nf, Wen, enb, xh, WSa, WSb, b1f, Sh, Dh,
                                    (_Float16*)agg, um, red);

  for (int l = 0; l < 4; l++) {
    msg_kernel<<<12500, 128, 0, stream>>>(
        Sh, Dh, efh, meta, cong,
        Wcp + (size_t)l * 8 * 512, Wm2 + (size_t)l * 32 * 512,
        w1cp + l * 128, mb2 + l * 128, agg);
    if (l < 3) {
      upd_kernel<false><<<782, 256, 0, stream>>>(
          xh, (_Float16*)agg,
          Wu1 + (size_t)l * 64 * 512, Wu2 + (size_t)l * 32 * 512,
          ub1 + l * 128, ub2 + l * 128, lnw + l * 128, lnb + l * 128,
          WSa + (size_t)(l + 1) * 32 * 512, WSb + (size_t)(l + 1) * 32 * 512,
          b1f + (l + 1) * 128, Sh, Dh, red);
    } else {
      upd_kernel<true><<<782, 256, 0, stream>>>(
          xh, (_Float16*)agg,
          Wu1 + (size_t)l * 64 * 512, Wu2 + (size_t)l * 32 * 512,
          ub1 + l * 128, ub2 + l * 128, lnw + l * 128, lnb + l * 128,
          (const _Float16*)nullptr, (const _Float16*)nullptr,
          (const float*)nullptr, Sh, Dh, red);
    }
  }

  readout_kernel<<<1, 128, 0, stream>>>(red, xw1, xb1, xw2, xb2,
                                        rw1, rb1, rw2, rb2, rw3, rb3, out);
}